// Round 15
// baseline (260.927 us; speedup 1.0000x reference)
//
#include <hip/hip_runtime.h>
#include <hip/hip_bf16.h>
#include <math.h>

// Problem constants
#define B_   2
#define S_   2048
#define C_   512
#define D_   768
#define H_   12
#define DH_  64
#define DFF_ 3072
#define NS_  (C_ + S_)   // 2560
#define LOG2E_ 1.44269504f

typedef __attribute__((ext_vector_type(8))) short          bf16x8;
typedef __attribute__((ext_vector_type(4))) float          f32x4;
typedef __attribute__((ext_vector_type(8))) unsigned short us8;
typedef __attribute__((ext_vector_type(4))) unsigned short us4;

static __device__ __forceinline__ unsigned short f2b(float f) {
    unsigned int u = __float_as_uint(f);
    unsigned int r = (u + 0x7FFFu + ((u >> 16) & 1u)) >> 16;   // RNE
    return (unsigned short)r;
}
static __device__ __forceinline__ float b2f(unsigned short u) {
    return __uint_as_float(((unsigned int)u) << 16);
}
// raw v_exp_f32: D = 2^S0 (1 instruction; exp2f libm path is ~6-8)
static __device__ __forceinline__ float fexp2(float x) {
    float r;
    asm("v_exp_f32 %0, %1" : "=v"(r) : "v"(x));
    return r;
}

// async global->LDS, 16B per lane; lptr must be wave-uniform base
#define ASYNC_LDS16(gp, lp)                                                     \
    __builtin_amdgcn_global_load_lds(                                           \
        (const __attribute__((address_space(1))) void*)(gp),                    \
        (__attribute__((address_space(3))) void*)(lp), 16, 0, 0)

// XCD-chunked bijective block remap (requires nwg % 8 == 0; all call sites hold)
#define XCD_SWIZZLE_2D(MB, NB, TM, TN)                                          \
    int nwg_ = gridDim.x * gridDim.y;                                           \
    int bid_ = blockIdx.y * gridDim.x + blockIdx.x;                             \
    int q8_  = nwg_ >> 3;                                                       \
    int swz_ = (bid_ & 7) * q8_ + (bid_ >> 3);                                  \
    int MB = (swz_ / gridDim.x) * (TM);                                         \
    int NB = (swz_ % gridDim.x) * (TN);

// ---------------------------------------------------------------------------
// LayerNorm over D=768 -> bf16 out. One block (256 threads) per row.
// ---------------------------------------------------------------------------
__global__ __launch_bounds__(256) void ln_kernel(const float* __restrict__ in,
                                                 const float* __restrict__ g,
                                                 const float* __restrict__ bta,
                                                 unsigned short* __restrict__ out)
{
    int row = blockIdx.x;
    int tid = threadIdx.x;
    const float* x = in + (size_t)row * D_;
    float v0 = x[tid], v1 = x[tid + 256], v2 = x[tid + 512];
    float s  = v0 + v1 + v2;
    float s2 = v0 * v0 + v1 * v1 + v2 * v2;
#pragma unroll
    for (int off = 32; off >= 1; off >>= 1) {
        s  += __shfl_down(s,  off, 64);
        s2 += __shfl_down(s2, off, 64);
    }
    __shared__ float sh[8];
    int lane = tid & 63, wv = tid >> 6;
    if (lane == 0) { sh[wv] = s; sh[4 + wv] = s2; }
    __syncthreads();
    s  = sh[0] + sh[1] + sh[2] + sh[3];
    s2 = sh[4] + sh[5] + sh[6] + sh[7];
    float mu   = s * (1.0f / D_);
    float var  = s2 * (1.0f / D_) - mu * mu;
    float rstd = rsqrtf(var + 1e-5f);
    unsigned short* o = out + (size_t)row * D_;
    o[tid]       = f2b((v0 - mu) * rstd * g[tid]       + bta[tid]);
    o[tid + 256] = f2b((v1 - mu) * rstd * g[tid + 256] + bta[tid + 256]);
    o[tid + 512] = f2b((v2 - mu) * rstd * g[tid + 512] + bta[tid + 512]);
}

// ---------------------------------------------------------------------------
// Fused prep: 5 weight transposes + ctx convert + LN1 in one dispatch.
// ---------------------------------------------------------------------------
__global__ __launch_bounds__(256) void wprep(
    const float* __restrict__ Wattn, const float* __restrict__ Wref,
    const float* __restrict__ Wproj, const float* __restrict__ W1,
    const float* __restrict__ W2,    const float* __restrict__ ctx,
    const float* __restrict__ x,     const float* __restrict__ ln1g,
    const float* __restrict__ ln1b,
    unsigned short* __restrict__ wattnT, unsigned short* __restrict__ wrefT,
    unsigned short* __restrict__ wprojT, unsigned short* __restrict__ w1T,
    unsigned short* __restrict__ w2T,    unsigned short* __restrict__ ctxb,
    unsigned short* __restrict__ hb)
{
    __shared__ float t[32][33];
    __shared__ float sh[8];
    int bid = blockIdx.x;
    int tid = threadIdx.x;

    if (bid >= 8832) {   // ---- LN1 segment ----
        int row = bid - 8832;
        const float* xr = x + (size_t)row * D_;
        float v0 = xr[tid], v1 = xr[tid + 256], v2 = xr[tid + 512];
        float s  = v0 + v1 + v2;
        float s2 = v0 * v0 + v1 * v1 + v2 * v2;
#pragma unroll
        for (int off = 32; off >= 1; off >>= 1) {
            s  += __shfl_down(s,  off, 64);
            s2 += __shfl_down(s2, off, 64);
        }
        int lane = tid & 63, wv = tid >> 6;
        if (lane == 0) { sh[wv] = s; sh[4 + wv] = s2; }
        __syncthreads();
        s  = sh[0] + sh[1] + sh[2] + sh[3];
        s2 = sh[4] + sh[5] + sh[6] + sh[7];
        float mu   = s * (1.0f / D_);
        float var  = s2 * (1.0f / D_) - mu * mu;
        float rstd = rsqrtf(var + 1e-5f);
        unsigned short* o = hb + (size_t)row * D_;
        o[tid]       = f2b((v0 - mu) * rstd * ln1g[tid]       + ln1b[tid]);
        o[tid + 256] = f2b((v1 - mu) * rstd * ln1g[tid + 256] + ln1b[tid + 256]);
        o[tid + 512] = f2b((v2 - mu) * rstd * ln1g[tid + 512] + ln1b[tid + 512]);
        return;
    }
    if (bid >= 8064) {   // ---- ctx convert ----
        int i = (bid - 8064) * 256 + tid;
        float4 v = ((const float4*)ctx)[i];
        us4 o = { f2b(v.x), f2b(v.y), f2b(v.z), f2b(v.w) };
        ((us4*)ctxb)[i] = o;
        return;
    }
    // ---- weight transpose segment ----
    const float* in; unsigned short* outp; int K, N, nt;
    if (bid < 1728)      {             in = Wattn; outp = wattnT; K = 768;  N = 2304; nt = 72; }
    else if (bid < 2880) { bid -= 1728; in = Wref;  outp = wrefT;  K = 768;  N = 1536; nt = 48; }
    else if (bid < 3456) { bid -= 2880; in = Wproj; outp = wprojT; K = 768;  N = 768;  nt = 24; }
    else if (bid < 5760) { bid -= 3456; in = W1;    outp = w1T;    K = 768;  N = 3072; nt = 96; }
    else                 { bid -= 5760; in = W2;    outp = w2T;    K = 3072; N = 768;  nt = 24; }
    int n0 = (bid % nt) * 32, k0 = (bid / nt) * 32;
    int tx = tid & 31, ty = tid >> 5;
#pragma unroll
    for (int i = 0; i < 32; i += 8)
        t[ty + i][tx] = in[(size_t)(k0 + ty + i) * N + n0 + tx];
    __syncthreads();
#pragma unroll
    for (int i = 0; i < 32; i += 8)
        outp[(size_t)(n0 + ty + i) * K + k0 + tx] = f2b(t[tx][ty + i]);
}

// ---------------------------------------------------------------------------
// Shared GEMM epilogue (scalar path, fp32-output kernels)
// ---------------------------------------------------------------------------
#define GEMM_EPI_ELEM()                                                         \
    {                                                                           \
        float v = accv[q] + bv;                                                 \
        if (ACT) v = v / (1.0f + __expf(-v));                                   \
        if (RESID) v += resid[(size_t)grow * N + gcol];                         \
        if (OUTBF) {                                                            \
            outb[(size_t)grow * N + gcol] = f2b(v);                             \
        } else if (SLICE) {                                                     \
            int bb = grow >> 11, ss = grow & 2047;                              \
            if (ss > 0)                                                         \
                outf[((size_t)(bb * 2047 + ss - 1)) * N + gcol] = v;            \
        } else {                                                                \
            outf[(size_t)grow * N + gcol] = v;                                  \
        }                                                                       \
    }

// Vectorized bf16 C-tile epilogue: stage into the (dead) 32KB A/B LDS as
// [128][128] bf16 with XOR swizzle col^((row&7)<<3) (XOR before +base), then
// 8x coalesced us8 stores per thread. LdsC = flat 16384-u16 region.
#define GEMM_EPI_BF16_VEC(ACT_)                                                 \
    {                                                                           \
        __syncthreads();  /* all waves done reading Als/Bls */                  \
        unsigned short* Cls = (unsigned short*)LdsAB;                           \
        _Pragma("unroll")                                                       \
        for (int m = 0; m < 4; ++m) {                                           \
            _Pragma("unroll")                                                   \
            for (int q = 0; q < 4; ++q) {                                       \
                int rl = wr * 64 + m * 16 + ((lane >> 4) << 2) + q;             \
                int rsw = (rl & 7) << 3;                                        \
                _Pragma("unroll")                                               \
                for (int n = 0; n < 4; ++n) {                                   \
                    int cl = wc * 64 + n * 16 + lc;                             \
                    float v = acc[m][n][q] + bias[nb + cl];                     \
                    if (ACT_) v = v / (1.0f + __expf(-v));                      \
                    Cls[rl * 128 + (cl ^ rsw)] = f2b(v);                        \
                }                                                               \
            }                                                                   \
        }                                                                       \
        __syncthreads();                                                        \
        _Pragma("unroll")                                                       \
        for (int i = 0; i < 8; ++i) {                                           \
            int u = tid + i * 256;          /* 2048 us8 units */                \
            int row = u >> 4, c8 = u & 15;                                      \
            us8 v = *(const us8*)&Cls[row * 128 + ((c8 * 8) ^ ((row & 7) << 3))]; \
            *(us8*)&outb[(size_t)(mb + row) * N + nb + c8 * 8] = v;             \
        }                                                                       \
    }

// ---------------------------------------------------------------------------
// Fused qkv + kvctx GEMM (both 128x128 tile, bf16 out, K=768). 672 blocks.
// ---------------------------------------------------------------------------
__global__ __launch_bounds__(256) void gemm_qkv_ctx(
    const unsigned short* __restrict__ hb, const unsigned short* __restrict__ wattnT,
    const float* __restrict__ battn, unsigned short* __restrict__ qkvb,
    const unsigned short* __restrict__ ctxb, const unsigned short* __restrict__ wrefT,
    const float* __restrict__ bref, unsigned short* __restrict__ kvctxb)
{
    __shared__ unsigned short LdsAB[2 * 128 * 64];   // A tile | B tile | C-stage
    unsigned short* Als = LdsAB;
    unsigned short* Bls = LdsAB + 128 * 64;

    int bid = blockIdx.x;
    const unsigned short *A, *BT; const float* bias; unsigned short* outb;
    int N, gx, nblk, sb;
    if (bid < 576) { A = hb;   BT = wattnT; bias = battn; outb = qkvb;   N = 2304; gx = 18; nblk = 576; sb = bid; }
    else           { A = ctxb; BT = wrefT;  bias = bref;  outb = kvctxb; N = 1536; gx = 12; nblk = 96;  sb = bid - 576; }
    int swz = (sb & 7) * (nblk >> 3) + (sb >> 3);
    int mb = (swz / gx) * 128, nb = (swz % gx) * 128;
    const int K = 768;

    int tid  = threadIdx.x;
    int lane = tid & 63, w = tid >> 6;
    int wr = w >> 1, wc = w & 1;
    int lc = lane & 15;

    f32x4 acc[4][4];
#pragma unroll
    for (int m = 0; m < 4; ++m)
#pragma unroll
        for (int n = 0; n < 4; ++n)
            acc[m][n] = (f32x4){0.f, 0.f, 0.f, 0.f};

    int srow = w * 32 + (lane >> 3);
    int scol = (lane & 7) * 8;
    const unsigned short* abase = A  + (size_t)(mb + srow) * K + scol;
    const unsigned short* bbase = BT + (size_t)(nb + srow) * K + scol;

    int arow_l = wr * 64 + lc;
    int brow_l = wc * 64 + lc;
    int kfrag  = (lane >> 4) * 8;

    for (int kk = 0; kk < K; kk += 64) {
        __syncthreads();
#pragma unroll
        for (int i = 0; i < 4; ++i) {
            ASYNC_LDS16(abase + (size_t)(i * 8) * K + kk,
                        (char*)Als + (w * 32 + i * 8) * 128);
            ASYNC_LDS16(bbase + (size_t)(i * 8) * K + kk,
                        (char*)Bls + (w * 32 + i * 8) * 128);
        }
        __syncthreads();
#pragma unroll
        for (int ks = 0; ks < 64; ks += 32) {
            bf16x8 af[4], bq[4];
#pragma unroll
            for (int m = 0; m < 4; ++m)
                af[m] = *(const bf16x8*)&Als[(arow_l + m * 16) * 64 + ks + kfrag];
#pragma unroll
            for (int n = 0; n < 4; ++n)
                bq[n] = *(const bf16x8*)&Bls[(brow_l + n * 16) * 64 + ks + kfrag];
#pragma unroll
            for (int m = 0; m < 4; ++m)
#pragma unroll
                for (int n = 0; n < 4; ++n)
                    acc[m][n] = __builtin_amdgcn_mfma_f32_16x16x32_bf16(
                        af[m], bq[n], acc[m][n], 0, 0, 0);
        }
    }

    GEMM_EPI_BF16_VEC(0)
}

// ---------------------------------------------------------------------------
// MFMA bf16 GEMM (m97 structure): 128x128 tile, 4 waves (2x2), BK=64.
// OUTBF=1 uses the vectorized LDS-staged epilogue.
// ---------------------------------------------------------------------------
template <int ACT, int RESID, int SLICE, int OUTBF>
__global__ __launch_bounds__(256) void gemm_mfma(
    const unsigned short* __restrict__ A,    // [M][K] bf16
    const unsigned short* __restrict__ BT,   // [N][K] bf16
    const float* __restrict__ bias,          // [N]
    const float* __restrict__ resid,         // [M][N] fp32 (if RESID)
    float* __restrict__ outf,                // if !OUTBF
    unsigned short* __restrict__ outb,       // if OUTBF
    int M, int N, int K)
{
    __shared__ unsigned short LdsAB[2 * 128 * 64];
    unsigned short* Als = LdsAB;
    unsigned short* Bls = LdsAB + 128 * 64;

    int tid  = threadIdx.x;
    int lane = tid & 63, w = tid >> 6;
    XCD_SWIZZLE_2D(mb, nb, 128, 128)
    int wr = w >> 1, wc = w & 1;
    int lc = lane & 15;

    f32x4 acc[4][4];
#pragma unroll
    for (int m = 0; m < 4; ++m)
#pragma unroll
        for (int n = 0; n < 4; ++n)
            acc[m][n] = (f32x4){0.f, 0.f, 0.f, 0.f};

    int srow = w * 32 + (lane >> 3);
    int scol = (lane & 7) * 8;
    const unsigned short* abase = A  + (size_t)(mb + srow) * K + scol;
    const unsigned short* bbase = BT + (size_t)(nb + srow) * K + scol;

    int arow_l = wr * 64 + lc;
    int brow_l = wc * 64 + lc;
    int kfrag  = (lane >> 4) * 8;

    for (int kk = 0; kk < K; kk += 64) {
        __syncthreads();
#pragma unroll
        for (int i = 0; i < 4; ++i) {
            ASYNC_LDS16(abase + (size_t)(i * 8) * K + kk,
                        (char*)Als + (w * 32 + i * 8) * 128);
            ASYNC_LDS16(bbase + (size_t)(i * 8) * K + kk,
                        (char*)Bls + (w * 32 + i * 8) * 128);
        }
        __syncthreads();
#pragma unroll
        for (int ks = 0; ks < 64; ks += 32) {
            bf16x8 af[4], bq[4];
#pragma unroll
            for (int m = 0; m < 4; ++m)
                af[m] = *(const bf16x8*)&Als[(arow_l + m * 16) * 64 + ks + kfrag];
#pragma unroll
            for (int n = 0; n < 4; ++n)
                bq[n] = *(const bf16x8*)&Bls[(brow_l + n * 16) * 64 + ks + kfrag];
#pragma unroll
            for (int m = 0; m < 4; ++m)
#pragma unroll
                for (int n = 0; n < 4; ++n)
                    acc[m][n] = __builtin_amdgcn_mfma_f32_16x16x32_bf16(
                        af[m], bq[n], acc[m][n], 0, 0, 0);
        }
    }

    if (OUTBF) {
        GEMM_EPI_BF16_VEC(ACT)
    } else {
#pragma unroll
        for (int m = 0; m < 4; ++m) {
            int grow0 = mb + wr * 64 + m * 16 + ((lane >> 4) << 2);
#pragma unroll
            for (int n = 0; n < 4; ++n) {
                int gcol = nb + wc * 64 + n * 16 + lc;
                float bv = bias[gcol];
#pragma unroll
                for (int q = 0; q < 4; ++q) {
                    int grow = grow0 + q;
                    float accv[4] = {acc[m][n][0], acc[m][n][1], acc[m][n][2], acc[m][n][3]};
                    GEMM_EPI_ELEM()
                }
            }
        }
    }
}

// ---------------------------------------------------------------------------
// MFMA bf16 GEMM, 64x128 tile, 4 waves (1x4). LDS 24KB -> ~6 blocks/CU.
// ---------------------------------------------------------------------------
template <int ACT, int RESID, int SLICE, int OUTBF>
__global__ __launch_bounds__(256) void gemm_mfma64(
    const unsigned short* __restrict__ A,    // [M][K] bf16
    const unsigned short* __restrict__ BT,   // [N][K] bf16
    const float* __restrict__ bias,          // [N]
    const float* __restrict__ resid,         // [M][N] fp32 (if RESID)
    float* __restrict__ outf,                // if !OUTBF
    unsigned short* __restrict__ outb,       // if OUTBF
    int M, int N, int K)
{
    __shared__ unsigned short Als[64 * 64];   // 8KB
    __shared__ unsigned short Bls[128 * 64];  // 16KB

    int tid  = threadIdx.x;
    int lane = tid & 63, w = tid >> 6;
    XCD_SWIZZLE_2D(mb, nb, 64, 128)

    f32x4 acc[4][2];
#pragma unroll
    for (int m = 0; m < 4; ++m)
#pragma unroll
        for (int n = 0; n < 2; ++n)
            acc[m][n] = (f32x4){0.f, 0.f, 0.f, 0.f};

    int srow = w * 8 + (lane >> 3);           // +32 per issue
    int scol = (lane & 7) * 8;
    const unsigned short* abase = A  + (size_t)(mb + srow) * K + scol;
    const unsigned short* bbase = BT + (size_t)(nb + srow) * K + scol;

    int arow_l = lane & 15;                   // + m*16
    int brow_l = w * 32 + (lane & 15);        // + n*16
    int kfrag  = (lane >> 4) * 8;

    for (int kk = 0; kk < K; kk += 64) {
        __syncthreads();
#pragma unroll
        for (int i = 0; i < 2; ++i)
            ASYNC_LDS16(abase + (size_t)(i * 32) * K + kk,
                        (char*)Als + i * 4096 + w * 1024);
#pragma unroll
        for (int i = 0; i < 4; ++i)
            ASYNC_LDS16(bbase + (size_t)(i * 32) * K + kk,
                        (char*)Bls + i * 4096 + w * 1024);
        __syncthreads();
#pragma unroll
        for (int ks = 0; ks < 64; ks += 32) {
            bf16x8 af[4], bq[2];
#pragma unroll
            for (int m = 0; m < 4; ++m)
                af[m] = *(const bf16x8*)&Als[(arow_l + m * 16) * 64 + ks + kfrag];
#pragma unroll
            for (int n = 0; n < 2; ++n)
                bq[n] = *(const bf16x8*)&Bls[(brow_l + n * 16) * 64 + ks + kfrag];
#pragma unroll
            for (int m = 0; m < 4; ++m)
#pragma unroll
                for (int n = 0; n < 2; ++n)
                    acc[m][n] = __builtin_amdgcn_mfma_f32_16x16x32_bf16(
                        af[m], bq[n], acc[m][n], 0, 0, 0);
        }
    }

#pragma unroll
    for (int m = 0; m < 4; ++m) {
        int grow0 = mb + m * 16 + ((lane >> 4) << 2);
#pragma unroll
        for (int n = 0; n < 2; ++n) {
            int gcol = nb + w * 32 + n * 16 + (lane & 15);
            float bv = bias[gcol];
#pragma unroll
            for (int q = 0; q < 4; ++q) {
                int grow = grow0 + q;
                float accv[4] = {acc[m][n][0], acc[m][n][1], acc[m][n][2], acc[m][n][3]};
                GEMM_EPI_ELEM()
            }
        }
    }
}

// ---------------------------------------------------------------------------
// Work table for attn: qt 0..10 whole; qt 11..15 split into two halves.
// ---------------------------------------------------------------------------
__device__ const int ATT_QT[21] = {10,9,8,7,6,5,15,15,14, 4,14,13,13,12, 3,12,11,11, 2,1,0};
__device__ const int ATT_T0[21] = { 0,0,0,0,0,0, 0,10, 0, 0,10, 0, 9, 0, 0, 9, 0, 8, 0,0,0};
__device__ const int ATT_T1[21] = {15,14,13,12,11,10,10,20,10, 9,19, 9,18, 9, 8,17, 8,16, 7,6,5};

// ---------------------------------------------------------------------------
// MFMA fused attention v9 (unchanged from round 14).
// ---------------------------------------------------------------------------
__global__ __launch_bounds__(512, 2) void attn_mfma(const unsigned short* __restrict__ qkv,
                                                    const unsigned short* __restrict__ kvctx,
                                                    const float* __restrict__ cabp,
                                                    const int* __restrict__ smpp,
                                                    unsigned short* __restrict__ aout,
                                                    float* __restrict__ Opart,
                                                    float* __restrict__ mlpart)
{
    __shared__ unsigned short Kls[128 * 64];    // 16KB swizzled K tile
    __shared__ unsigned short Vt [64 * 136];    // 17KB V^T [d][k'], stride 136
    __shared__ unsigned short Pls[128 * 136];   // 34KB P [q][k'], stride 136

    int bid = blockIdx.x;
    int j = (bid < 256) ? bid : 503 - (bid - 256);   // desc-asc complementary map
    int rank = j / 24, grp = j % 24;
    int h = grp % 12, b = grp / 12;
    int qt = ATT_QT[rank], t0 = ATT_T0[rank], t1 = ATT_T1[rank];
    bool split = (t1 - t0) < (qt + 5);
    int half = (t0 > 0) ? 1 : 0;

    int tid = threadIdx.x;
    int l = tid & 63, w = tid >> 6;             // wave 0..7
    int g = l >> 4, lc = l & 15;
    float cab = *cabp;
    int   smp = *smpp;
    int qbase = qt * 128;

    // --- Q fragments (pre-scaled by log2e): q = qbase + w*16 + lc ---
    bf16x8 qf0, qf1;
    {
        const unsigned short* qp = qkv + ((size_t)(b * S_ + qbase + w * 16 + lc)) * (3 * D_)
                                       + h * DH_ + g * 8;
        qf0 = *(const bf16x8*)(qp);
        qf1 = *(const bf16x8*)(qp + 32);
#pragma unroll
        for (int i = 0; i < 8; ++i) {
            qf0[i] = (short)f2b(b2f((unsigned short)qf0[i]) * LOG2E_);
            qf1[i] = (short)f2b(b2f((unsigned short)qf1[i]) * LOG2E_);
        }
    }

    // all-ones bf16 B-fragment for the l-sum MFMA (1.0 = 0x3F80)
    bf16x8 vones;
#pragma unroll
    for (int i = 0; i < 8; ++i) vones[i] = (short)0x3F80;

    f32x4 acc[4];
#pragma unroll
    for (int n = 0; n < 4; ++n) acc[n] = (f32x4){0.f, 0.f, 0.f, 0.f};
    f32x4 lacc = (f32x4){0.f, 0.f, 0.f, 0.f};   // row-sum of P, D-layout
    float mrow[4];
#pragma unroll
    for (int e = 0; e < 4; ++e) mrow[e] = -1e30f;

    // staging lane geometry (all loop-invariant)
    int colu = 8 * ((l & 7) ^ (l >> 3));        // pre-swizzled global col (bf16)
    int kvr  = tid >> 3;                        // V k-row 0..63 (+64 second half)
    int d0   = (tid & 7) * 8;                   // V d chunk base
    int dsw  = (tid & 7) << 3;                  // Vt k-swizzle
    int vtrow[8];
#pragma unroll
    for (int jj = 0; jj < 8; ++jj) vtrow[jj] = (d0 + jj) * 136;
    int vo0 = kvr ^ dsw, vo1 = (64 + kvr) ^ dsw;
    int ksw  = (lc & 7) << 3;                   // K-read swizzle (nf-independent)
    int koff0 = (g * 8) ^ ksw, koff1 = (32 + g * 8) ^ ksw;
    us8 vr0, vr1;

#define STAGE_TILE(TT)                                                                   \
    {                                                                                    \
        int kb2 = (TT) * 128;                                                            \
        bool isctx = (kb2 < C_);                                                         \
        _Pragma("unroll")                                                                \
        for (int s2 = 0; s2 < 2; ++s2) {                                                 \
            int s = w * 2 + s2;                                                          \
            int kj = kb2 + s * 8 + (l >> 3);                                             \
            const unsigned short* src = isctx                                            \
                ? kvctx + ((size_t)(b * C_ + kj)) * (2 * D_) + h * DH_ + colu            \
                : qkv + ((size_t)(b * S_ + kj - C_)) * (3 * D_) + D_ + h * DH_ + colu;   \
            ASYNC_LDS16(src, (char*)Kls + s * 1024);                                     \
        }                                                                                \
        int kv0 = kb2 + kvr;                                                             \
        vr0 = *(const us8*)(isctx                                                        \
            ? kvctx + ((size_t)(b * C_ + kv0)) * (2 * D_) + D_ + h * DH_ + d0            \
            : qkv + ((size_t)(b * S_ + kv0 - C_)) * (3 * D_) + 2 * D_ + h * DH_ + d0);   \
        vr1 = *(const us8*)(isctx                                                        \
            ? kvctx + ((size_t)(b * C_ + kv0 + 64)) * (2 * D_) + D_ + h * DH_ + d0       \
            : qkv + ((size_t)(b * S_ + kv0 + 64 - C_)) * (3 * D_) + 2 * D_ + h * DH_ + d0); \
    }

    STAGE_TILE(t0)

    for (int t = t0; t < t1; ++t) {
        int kb = t * 128;
        __syncthreads();   // staging visible; prev PV done reading Vt/Pls

        // ---- V^T scatter: 16 stores, loop-invariant addresses ----
#pragma unroll
        for (int jj = 0; jj < 8; ++jj) {
            Vt[vtrow[jj] + vo0] = vr0[jj];
            Vt[vtrow[jj] + vo1] = vr1[jj];
        }

        // ---- QK^T: S[16q x 128k] per wave (log2 units) ----
        f32x4 s4[8];
#pragma unroll
        for (int nf = 0; nf < 8; ++nf) s4[nf] = (f32x4){0.f, 0.f, 0.f, 0.f};
        __builtin_amdgcn_s_setprio(1);
#pragma unroll
        for (int nf = 0; nf < 8; ++nf) {
            bf16x8 kf0 = *(const bf16x8*)&Kls[(nf * 16 + lc) * 64 + koff0];
            bf16x8 kf1 = *(const bf16x8*)&Kls[(nf * 16 + lc) * 64 + koff1];
            s4[nf] = __builtin_amdgcn_mfma_f32_16x16x32_bf16(qf0, kf0, s4[nf], 0, 0, 0);
            s4[nf] = __builtin_amdgcn_mfma_f32_16x16x32_bf16(qf1, kf1, s4[nf], 0, 0, 0);
        }
        __builtin_amdgcn_s_setprio(0);

        // ---- tile classification (global tile index semantics) ----
        bool edge_t = (t == qt + 4);
        bool diag_t = (kb == qbase) && (smp > 0);
        float tb = (kb < C_) ? cab * LOG2E_ : 0.0f;

        if (edge_t) {
#pragma unroll
            for (int nf = 0; nf < 8; ++nf) {
                int kj = kb + nf * 16 + lc;
#pragma unroll
                for (int e = 0; e < 4; ++e) {
                    int qi = qbase + w * 16 + g * 4 + e;
                    s4[nf][e] = (kj <= qi + C_) ? s4[nf][e] : -100000.0f;
                }
            }
        }
        if (diag_t) {
#pragma unroll
            for (int nf = 0; nf < 8; ++nf) {
                int kj = kb + nf * 16 + lc;
#pragma unroll
                for (int e = 0; e < 4; ++e) {
                    int qi = qbase + w * 16 + g * 4 + e;
                    if (kj == qi) s4[nf][e] = -100000.0f;
                }
            }
        }

        // ---- online softmax (log2 units, raw v_exp_f32, l via MFMA) ----
        float tmax[4], mbase[4];
#pragma unroll
        for (int e = 0; e < 4; ++e) {
            float u0 = fmaxf(fmaxf(s4[0][e], s4[1][e]), fmaxf(s4[2][e], s4[3][e]));
            float u1 = fmaxf(fmaxf(s4[4][e], s4[5][e]), fmaxf(s4[6][e], s4[7][e]));
            tmax[e] = fmaxf(u0, u1);
        }
#pragma unroll
        for (int e = 0; e < 4; ++e) {
            tmax[e] = fmaxf(tmax[e], __shfl_xor(tmax[e], 1));
            tmax[e] = fmaxf(tmax[e], __shfl_xor(tmax[e], 2));
            tmax[e] = fmaxf(tmax[e], __shfl_xor(tmax[e], 4));
            tmax[e] = fmaxf(tmax[e], __shfl_xor(tmax[e], 8));
        }
#pragma unroll
        for (int e = 0; e < 4; ++e) {
            float mn = fmaxf(mrow[e], tmax[e] + tb);
            if (mn > mrow[e]) {                      // defer-rescale (O and l together)
                float sc = fexp2(mrow[e] - mn);
#pragma unroll
                for (int nf2 = 0; nf2 < 4; ++nf2) acc[nf2][e] *= sc;
                lacc[e] *= sc;
                mrow[e] = mn;
            }
            mbase[e] = mrow[e] - tb;
        }
#pragma unroll
        for (int nf = 0; nf < 8; ++nf)
#pragma unroll
            for (int e = 0; e < 4; ++e)
                s4[nf][e] = fexp2(s4[nf][e] - mbase[e]);

        // ---- P -> bf16 via cvt_pk -> swizzled LDS (offset XOR before +base) ----
#pragma unroll
        for (int e = 0; e < 4; ++e) {
            int q = w * 16 + g * 4 + e;
            int qrow = q * 136, qsw = (q & 7) << 3;
#pragma unroll
            for (int a = 0; a < 4; ++a) {
                unsigned int pk;
                asm("v_cvt_pk_bf16_f32 %0, %1, %2"
                    : "=v"(pk) : "v"(s4[2 * a][e]), "v"(s4[2 * a + 1][e]));
                int xk = (a * 32 + lc) ^ qsw;
                Pls[qrow + xk]        = (unsigned short)pk;
                Pls[qrow + (xk ^ 16)] = (unsigned short)(pk >> 16);
            }
        }

        __syncthreads();   // Vt/Pls complete; Kls reads done -> safe to restage

        // ---- stage next tile under PV ----
        if (t + 1 < t1) STAGE_TILE(t + 1)

        // ---- PV: O[16q x 64d] += P @ V ;  l += P @ ones ----
        {
            int qa = w * 16 + lc;
            int qrow = qa * 136, qsw = (qa & 7) << 3;
            __builtin_amdgcn_s_setprio(1);
#pragma unroll
            for (int ks2 = 0; ks2 < 4; ++ks2) {
                bf16x8 pf = *(const bf16x8*)&Pls[qrow + ((ks2 * 32 + g * 8) ^ qsw)];
#pragma unroll
                for (int nf2 = 0; nf2 < 4; ++nf2) {
                    int d = nf2 * 16 + lc;
                    bf16x8 vf = *(const bf16x8*)&Vt[d * 136 +
                                   ((ks2 * 32 + g * 8) ^ (((d >> 3) & 7) << 3))];
                    acc[nf2] = __builtin_amdgcn_mfma_f32_16x16x32_bf16(pf, vf, acc[nf2], 0, 0, 0);
                }
                lacc = __builtin_amdgcn_mfma_f32_16x16x32_bf16(pf, vones, lacc, 0, 0, 0);
            }
            __builtin_amdgcn_s_setprio(0);
        }
    }

    // ---- epilogue: lacc[e] is already the complete row sum (no reduce) ----
    if (!split) {
#pragma unroll
        for (int e = 0; e < 4; ++e) {
            int q = qbase + w * 16 + g * 4 + e;
            float inv = 1.0f / lacc[e];
            unsigned short* dst = &aout[((size_t)(b * S_ + q)) * D_ + h * DH_];
#pragma unroll
            for (int nf2 = 0; nf2 < 4; ++nf2)
                dst[nf2 * 16 + lc] = f2b(acc[nf2][e] * inv);
        }
    } else {
        int rec = ((b * 12 + h) * 5 + (qt - 11)) * 2 + half;
        float* Ob  = Opart + (size_t)rec * 8192;
        float* mlb = mlpart + rec * 256;
#pragma unroll
        for (int e = 0; e < 4; ++e) {
            int row = w * 16 + g * 4 + e;
#pragma unroll
            for (int nf2 = 0; nf2 < 4; ++nf2)
                Ob[row * 64 + nf2 * 16 + lc] = acc[nf2][e];
            if (lc == 0) { mlb[row * 2] = mrow[e]; mlb[row * 2 + 1] = lacc[e]; }
        }
    }
#undef STAGE_TILE
}

// ---------------------------------------------------------------------------
// Merge split-KV halves (log2 units): c_i = 2^(m_i - m) via v_exp_f32.
// ---------------------------------------------------------------------------
__global__ __launch_bounds__(256) void attn_merge(const float* __restrict__ Opart,
                                                  const float* __restrict__ mlpart,
                                                  unsigned short* __restrict__ aout)
{
    int rec = blockIdx.x;                 // (b*12+h)*5 + qidx
    int qidx = rec % 5;
    int bh = rec / 5;
    int h = bh % 12, b = bh / 12;
    int qt = 11 + qidx;
    int row = threadIdx.x >> 1, dbase = (threadIdx.x & 1) * 32;

    const float* O0  = Opart + ((size_t)(rec * 2 + 0)) * 8192 + row * 64 + dbase;
    const float* O1  = Opart + ((size_t)(rec * 2 + 1)) * 8192 + row * 64 + dbase;
    const float* ml0 = mlpart + (rec * 2 + 0) * 256 + row * 2;
    const float* ml1 = mlpart + (rec * 2 + 1) * 256 + row * 2;
    float m0 = ml0[0], l0 = ml0[1];
    float m1 = ml1[0], l1 = ml1[1];
    float m  = fmaxf(m0, m1);
    float c0 = fexp2(m0 - m), c1 = fexp2(m1 - m);
    float inv = 1.0f / (l0 * c0 + l1 * c1);

    int q = qt * 128 + row;
    unsigned short* dst = &aout[((size_t)(b * S_ + q)) * D_ + h * DH_ + dbase];
#pragma unroll
    for (int jj = 0; jj < 32; ++jj)
        dst[jj] = f2b((O0[jj] * c0 + O1[jj] * c1) * inv);
}

// ---------------------------------------------------------------------------
extern "C" void kernel_launch(void* const* d_in, const int* in_sizes, int n_in,
                              void* d_out, int out_size, void* d_ws, size_t ws_size,
                              hipStream_t stream)
{
    const float* x     = (const float*)d_in[0];
    const float* ctx   = (const float*)d_in[1];
    const float* ln1g  = (const float*)d_in[2];
    const float* ln1b  = (const float*)d_in[3];
    const float* Wattn = (const float*)d_in[4];
    const float* battn = (const float*)d_in[5];
    const float* Wref  = (const float*)d_in[6];
    const float* bref  = (const float*)d_in[7];
    const float* Wproj = (const float*)d_in[8];
    const float* bproj = (const float*)d_in[9];
    const float* ln2g  = (const float*)d_in[10];
    const float* ln2b  = (const float*)d_in[11];
    const float* W1    = (const float*)d_in[12];
    const float* b1    = (const float*)d_in[13];
    const float* W2    = (const float*)d_in[14];
    const float* b2    = (const float*)d_in[15];
    const float* cab   = (const float*)d_in[16];
    const int*   smp   = (const int*)d_in[17];
    float* out = (float*)d_out;

    // ---- workspace layout (float units) ----
    float* ws = (float*)d_ws;
    unsigned short* qkvb   = (unsigned short*)(ws + 0);          // 4096x2304 bf16 (steps 2-4)
    unsigned short* ff1b   = (unsigned short*)(ws + 0);          // 4096x3072 bf16 (steps 7-8)
    unsigned short* kvctxb = (unsigned short*)(ws + 4718592);    // 1024x1536 bf16
    unsigned short* attnb  = (unsigned short*)(ws + 5505024);    // 4096x768 bf16 (ends 7077888)
    unsigned short* hb     = (unsigned short*)(ws + 7077888);    // 4096x768 bf16 (ends 8650752)
    float*          x1     = ws + 8650752;                       // 4096x768 fp32 (ends 11796480)
    // attn split partials overlay hb+x1 region (dead during attention):
    float*          Opart  = ws + 7077888;                       // 3,932,160 fl (ends 11010048)
    float*          mlpart = ws + 11010048;                      // 61,440 fl  (ends 11071488)
    unsigned short* ctxb   = (unsigned short*)(ws + 11796480);   // 1024x768 bf16 (ends 12189696)
    unsigned short* wts    = (unsigned short*)(ws + 12189696);   // bf16 weights
    unsigned short* wattnT = wts;                                // 2304x768
    unsigned short* wrefT  = wts + 1769472;                      // 1536x768
    unsigned short* wprojT = wts + 2949120;                      // 768x768
    unsigned short* w1T    = wts + 3538944;                      // 3072x768
    unsigned short* w2T    = wts + 5898240;                      // 768x3072

    // 0. fused prep: 5 transposes + ctx convert + LN1 (one dispatch)
    wprep<<<12928, 256, 0, stream>>>(Wattn, Wref, Wproj, W1, W2, ctx, x, ln1g, ln1b,
                                     wattnT, wrefT, wprojT, w1T, w2T, ctxb, hb);
    // 1. qkv + kvctx fused GEMM (672 blocks, vectorized epilogue)
    gemm_qkv_ctx<<<672, 256, 0, stream>>>(hb, wattnT, battn, qkvb,
                                          ctxb, wrefT, bref, kvctxb);
    // 2. attention (split-KV balanced, l-via-MFMA) + merge
    attn_mfma<<<504, 512, 0, stream>>>(qkvb, kvctxb, cab, smp, attnb, Opart, mlpart);
    attn_merge<<<120, 256, 0, stream>>>(Opart, mlpart, attnb);
    // 3. x1 = x + attn @ Wproj + bproj  (64x128 tile, 384 blocks)
    gemm_mfma64<0, 1, 0, 0><<<dim3(6, 64), 256, 0, stream>>>(
        attnb, wprojT, bproj, x, x1, nullptr, 4096, 768, 768);
    // 4. h = LN2(x1)
    ln_kernel<<<B_ * S_, 256, 0, stream>>>(x1, ln2g, ln2b, hb);
    // 5. ff1 = silu(h @ W1 + b1)   (128x128 tile, 768 blocks, vectorized epi)
    gemm_mfma<1, 0, 0, 1><<<dim3(24, 32), 256, 0, stream>>>(
        hb, w1T, b1, nullptr, nullptr, ff1b, 4096, 3072, 768);
    // 6. out = slice(x1 + ff1 @ W2 + b2)  (64x128 tile, 384 blocks)
    gemm_mfma64<0, 1, 1, 0><<<dim3(6, 64), 256, 0, stream>>>(
        ff1b, w2T, b2, x1, out, nullptr, 4096, 768, 3072);
}

// Round 16
// 259.469 us; speedup vs baseline: 1.0056x; 1.0056x over previous
//
#include <hip/hip_runtime.h>
#include <hip/hip_bf16.h>
#include <math.h>

// Problem constants
#define B_   2
#define S_   2048
#define C_   512
#define D_   768
#define H_   12
#define DH_  64
#define DFF_ 3072
#define NS_  (C_ + S_)   // 2560
#define LOG2E_ 1.44269504f

typedef __attribute__((ext_vector_type(8))) short          bf16x8;
typedef __attribute__((ext_vector_type(4))) float          f32x4;
typedef __attribute__((ext_vector_type(8))) unsigned short us8;
typedef __attribute__((ext_vector_type(4))) unsigned short us4;

static __device__ __forceinline__ unsigned short f2b(float f) {
    unsigned int u = __float_as_uint(f);
    unsigned int r = (u + 0x7FFFu + ((u >> 16) & 1u)) >> 16;   // RNE
    return (unsigned short)r;
}
static __device__ __forceinline__ float b2f(unsigned short u) {
    return __uint_as_float(((unsigned int)u) << 16);
}
// raw v_exp_f32: D = 2^S0 (1 instruction; exp2f libm path is ~6-8)
static __device__ __forceinline__ float fexp2(float x) {
    float r;
    asm("v_exp_f32 %0, %1" : "=v"(r) : "v"(x));
    return r;
}

// async global->LDS, 16B per lane; lptr must be wave-uniform base
#define ASYNC_LDS16(gp, lp)                                                     \
    __builtin_amdgcn_global_load_lds(                                           \
        (const __attribute__((address_space(1))) void*)(gp),                    \
        (__attribute__((address_space(3))) void*)(lp), 16, 0, 0)

// XCD-chunked bijective block remap (requires nwg % 8 == 0; all call sites hold)
#define XCD_SWIZZLE_2D(MB, NB, TM, TN)                                          \
    int nwg_ = gridDim.x * gridDim.y;                                           \
    int bid_ = blockIdx.y * gridDim.x + blockIdx.x;                             \
    int q8_  = nwg_ >> 3;                                                       \
    int swz_ = (bid_ & 7) * q8_ + (bid_ >> 3);                                  \
    int MB = (swz_ / gridDim.x) * (TM);                                         \
    int NB = (swz_ % gridDim.x) * (TN);

// ---------------------------------------------------------------------------
// LayerNorm over D=768 -> bf16 out. One block (256 threads) per row.
// ---------------------------------------------------------------------------
__global__ __launch_bounds__(256) void ln_kernel(const float* __restrict__ in,
                                                 const float* __restrict__ g,
                                                 const float* __restrict__ bta,
                                                 unsigned short* __restrict__ out)
{
    int row = blockIdx.x;
    int tid = threadIdx.x;
    const float* x = in + (size_t)row * D_;
    float v0 = x[tid], v1 = x[tid + 256], v2 = x[tid + 512];
    float s  = v0 + v1 + v2;
    float s2 = v0 * v0 + v1 * v1 + v2 * v2;
#pragma unroll
    for (int off = 32; off >= 1; off >>= 1) {
        s  += __shfl_down(s,  off, 64);
        s2 += __shfl_down(s2, off, 64);
    }
    __shared__ float sh[8];
    int lane = tid & 63, wv = tid >> 6;
    if (lane == 0) { sh[wv] = s; sh[4 + wv] = s2; }
    __syncthreads();
    s  = sh[0] + sh[1] + sh[2] + sh[3];
    s2 = sh[4] + sh[5] + sh[6] + sh[7];
    float mu   = s * (1.0f / D_);
    float var  = s2 * (1.0f / D_) - mu * mu;
    float rstd = rsqrtf(var + 1e-5f);
    unsigned short* o = out + (size_t)row * D_;
    o[tid]       = f2b((v0 - mu) * rstd * g[tid]       + bta[tid]);
    o[tid + 256] = f2b((v1 - mu) * rstd * g[tid + 256] + bta[tid + 256]);
    o[tid + 512] = f2b((v2 - mu) * rstd * g[tid + 512] + bta[tid + 512]);
}

// ---------------------------------------------------------------------------
// Fused prep: 5 weight transposes + ctx convert + LN1 in one dispatch.
// Transpose segment vectorized: 1x float4 load + 1x us4 store per thread
// (was 4x scalar load + 4x u16 store). LDS col-read 2-way conflict = free.
// ---------------------------------------------------------------------------
__global__ __launch_bounds__(256) void wprep(
    const float* __restrict__ Wattn, const float* __restrict__ Wref,
    const float* __restrict__ Wproj, const float* __restrict__ W1,
    const float* __restrict__ W2,    const float* __restrict__ ctx,
    const float* __restrict__ x,     const float* __restrict__ ln1g,
    const float* __restrict__ ln1b,
    unsigned short* __restrict__ wattnT, unsigned short* __restrict__ wrefT,
    unsigned short* __restrict__ wprojT, unsigned short* __restrict__ w1T,
    unsigned short* __restrict__ w2T,    unsigned short* __restrict__ ctxb,
    unsigned short* __restrict__ hb)
{
    __shared__ float t[32][33];
    __shared__ float sh[8];
    int bid = blockIdx.x;
    int tid = threadIdx.x;

    if (bid >= 8832) {   // ---- LN1 segment ----
        int row = bid - 8832;
        const float* xr = x + (size_t)row * D_;
        float v0 = xr[tid], v1 = xr[tid + 256], v2 = xr[tid + 512];
        float s  = v0 + v1 + v2;
        float s2 = v0 * v0 + v1 * v1 + v2 * v2;
#pragma unroll
        for (int off = 32; off >= 1; off >>= 1) {
            s  += __shfl_down(s,  off, 64);
            s2 += __shfl_down(s2, off, 64);
        }
        int lane = tid & 63, wv = tid >> 6;
        if (lane == 0) { sh[wv] = s; sh[4 + wv] = s2; }
        __syncthreads();
        s  = sh[0] + sh[1] + sh[2] + sh[3];
        s2 = sh[4] + sh[5] + sh[6] + sh[7];
        float mu   = s * (1.0f / D_);
        float var  = s2 * (1.0f / D_) - mu * mu;
        float rstd = rsqrtf(var + 1e-5f);
        unsigned short* o = hb + (size_t)row * D_;
        o[tid]       = f2b((v0 - mu) * rstd * ln1g[tid]       + ln1b[tid]);
        o[tid + 256] = f2b((v1 - mu) * rstd * ln1g[tid + 256] + ln1b[tid + 256]);
        o[tid + 512] = f2b((v2 - mu) * rstd * ln1g[tid + 512] + ln1b[tid + 512]);
        return;
    }
    if (bid >= 8064) {   // ---- ctx convert ----
        int i = (bid - 8064) * 256 + tid;
        float4 v = ((const float4*)ctx)[i];
        us4 o = { f2b(v.x), f2b(v.y), f2b(v.z), f2b(v.w) };
        ((us4*)ctxb)[i] = o;
        return;
    }
    // ---- weight transpose segment (vectorized) ----
    const float* in; unsigned short* outp; int K, N, nt;
    if (bid < 1728)      {             in = Wattn; outp = wattnT; K = 768;  N = 2304; nt = 72; }
    else if (bid < 2880) { bid -= 1728; in = Wref;  outp = wrefT;  K = 768;  N = 1536; nt = 48; }
    else if (bid < 3456) { bid -= 2880; in = Wproj; outp = wprojT; K = 768;  N = 768;  nt = 24; }
    else if (bid < 5760) { bid -= 3456; in = W1;    outp = w1T;    K = 768;  N = 3072; nt = 96; }
    else                 { bid -= 5760; in = W2;    outp = w2T;    K = 3072; N = 768;  nt = 24; }
    int n0 = (bid % nt) * 32, k0 = (bid / nt) * 32;
    int r  = tid >> 3;            // 0..31
    int c4 = (tid & 7) * 4;       // 0,4,..,28
    float4 v4 = *(const float4*)&in[(size_t)(k0 + r) * N + n0 + c4];
    t[r][c4]     = v4.x;
    t[r][c4 + 1] = v4.y;
    t[r][c4 + 2] = v4.z;
    t[r][c4 + 3] = v4.w;
    __syncthreads();
    // write: out[n0+r][k0+c4 .. +3] = in[k0+c4 .. +3][n0+r] = t[c4+i][r]
    us4 ov = { f2b(t[c4][r]), f2b(t[c4 + 1][r]), f2b(t[c4 + 2][r]), f2b(t[c4 + 3][r]) };
    *(us4*)&outp[(size_t)(n0 + r) * K + k0 + c4] = ov;
}

// ---------------------------------------------------------------------------
// Shared GEMM epilogue
// ---------------------------------------------------------------------------
#define GEMM_EPI_ELEM()                                                         \
    {                                                                           \
        float v = accv[q] + bv;                                                 \
        if (ACT) v = v / (1.0f + __expf(-v));                                   \
        if (RESID) v += resid[(size_t)grow * N + gcol];                         \
        if (OUTBF) {                                                            \
            outb[(size_t)grow * N + gcol] = f2b(v);                             \
        } else if (SLICE) {                                                     \
            int bb = grow >> 11, ss = grow & 2047;                              \
            if (ss > 0)                                                         \
                outf[((size_t)(bb * 2047 + ss - 1)) * N + gcol] = v;            \
        } else {                                                                \
            outf[(size_t)grow * N + gcol] = v;                                  \
        }                                                                       \
    }

// ---------------------------------------------------------------------------
// Fused qkv + kvctx GEMM (both 128x128 tile, OUTBF, K=768). 672 blocks.
// ---------------------------------------------------------------------------
__global__ __launch_bounds__(256) void gemm_qkv_ctx(
    const unsigned short* __restrict__ hb, const unsigned short* __restrict__ wattnT,
    const float* __restrict__ battn, unsigned short* __restrict__ qkvb,
    const unsigned short* __restrict__ ctxb, const unsigned short* __restrict__ wrefT,
    const float* __restrict__ bref, unsigned short* __restrict__ kvctxb)
{
    __shared__ unsigned short Als[128 * 64];
    __shared__ unsigned short Bls[128 * 64];

    int bid = blockIdx.x;
    const unsigned short *A, *BT; const float* bias; unsigned short* outb;
    int N, gx, nblk, sb;
    if (bid < 576) { A = hb;   BT = wattnT; bias = battn; outb = qkvb;   N = 2304; gx = 18; nblk = 576; sb = bid; }
    else           { A = ctxb; BT = wrefT;  bias = bref;  outb = kvctxb; N = 1536; gx = 12; nblk = 96;  sb = bid - 576; }
    int swz = (sb & 7) * (nblk >> 3) + (sb >> 3);
    int mb = (swz / gx) * 128, nb = (swz % gx) * 128;
    const int K = 768;

    int tid  = threadIdx.x;
    int lane = tid & 63, w = tid >> 6;
    int wr = w >> 1, wc = w & 1;

    f32x4 acc[4][4];
#pragma unroll
    for (int m = 0; m < 4; ++m)
#pragma unroll
        for (int n = 0; n < 4; ++n)
            acc[m][n] = (f32x4){0.f, 0.f, 0.f, 0.f};

    int srow = w * 32 + (lane >> 3);
    int scol = (lane & 7) * 8;
    const unsigned short* abase = A  + (size_t)(mb + srow) * K + scol;
    const unsigned short* bbase = BT + (size_t)(nb + srow) * K + scol;

    int arow_l = wr * 64 + (lane & 15);
    int brow_l = wc * 64 + (lane & 15);
    int kfrag  = (lane >> 4) * 8;

    for (int kk = 0; kk < K; kk += 64) {
        __syncthreads();
#pragma unroll
        for (int i = 0; i < 4; ++i) {
            ASYNC_LDS16(abase + (size_t)(i * 8) * K + kk,
                        (char*)Als + (w * 32 + i * 8) * 128);
            ASYNC_LDS16(bbase + (size_t)(i * 8) * K + kk,
                        (char*)Bls + (w * 32 + i * 8) * 128);
        }
        __syncthreads();
#pragma unroll
        for (int ks = 0; ks < 64; ks += 32) {
            bf16x8 af[4], bq[4];
#pragma unroll
            for (int m = 0; m < 4; ++m)
                af[m] = *(const bf16x8*)&Als[(arow_l + m * 16) * 64 + ks + kfrag];
#pragma unroll
            for (int n = 0; n < 4; ++n)
                bq[n] = *(const bf16x8*)&Bls[(brow_l + n * 16) * 64 + ks + kfrag];
#pragma unroll
            for (int m = 0; m < 4; ++m)
#pragma unroll
                for (int n = 0; n < 4; ++n)
                    acc[m][n] = __builtin_amdgcn_mfma_f32_16x16x32_bf16(
                        af[m], bq[n], acc[m][n], 0, 0, 0);
        }
    }

#pragma unroll
    for (int m = 0; m < 4; ++m) {
        int grow0 = mb + wr * 64 + m * 16 + ((lane >> 4) << 2);
#pragma unroll
        for (int n = 0; n < 4; ++n) {
            int gcol = nb + wc * 64 + n * 16 + (lane & 15);
            float bv = bias[gcol];
#pragma unroll
            for (int q = 0; q < 4; ++q) {
                int grow = grow0 + q;
                outb[(size_t)grow * N + gcol] = f2b(acc[m][n][q] + bv);
            }
        }
    }
}

// ---------------------------------------------------------------------------
// MFMA bf16 GEMM (m97 structure): 128x128 tile, 4 waves (2x2), BK=64.
// ---------------------------------------------------------------------------
template <int ACT, int RESID, int SLICE, int OUTBF>
__global__ __launch_bounds__(256) void gemm_mfma(
    const unsigned short* __restrict__ A,    // [M][K] bf16
    const unsigned short* __restrict__ BT,   // [N][K] bf16
    const float* __restrict__ bias,          // [N]
    const float* __restrict__ resid,         // [M][N] fp32 (if RESID)
    float* __restrict__ outf,                // if !OUTBF
    unsigned short* __restrict__ outb,       // if OUTBF
    int M, int N, int K)
{
    __shared__ unsigned short Als[128 * 64];
    __shared__ unsigned short Bls[128 * 64];

    int tid  = threadIdx.x;
    int lane = tid & 63, w = tid >> 6;
    XCD_SWIZZLE_2D(mb, nb, 128, 128)
    int wr = w >> 1, wc = w & 1;

    f32x4 acc[4][4];
#pragma unroll
    for (int m = 0; m < 4; ++m)
#pragma unroll
        for (int n = 0; n < 4; ++n)
            acc[m][n] = (f32x4){0.f, 0.f, 0.f, 0.f};

    int srow = w * 32 + (lane >> 3);
    int scol = (lane & 7) * 8;
    const unsigned short* abase = A  + (size_t)(mb + srow) * K + scol;
    const unsigned short* bbase = BT + (size_t)(nb + srow) * K + scol;

    int arow_l = wr * 64 + (lane & 15);
    int brow_l = wc * 64 + (lane & 15);
    int kfrag  = (lane >> 4) * 8;

    for (int kk = 0; kk < K; kk += 64) {
        __syncthreads();
#pragma unroll
        for (int i = 0; i < 4; ++i) {
            ASYNC_LDS16(abase + (size_t)(i * 8) * K + kk,
                        (char*)Als + (w * 32 + i * 8) * 128);
            ASYNC_LDS16(bbase + (size_t)(i * 8) * K + kk,
                        (char*)Bls + (w * 32 + i * 8) * 128);
        }
        __syncthreads();
#pragma unroll
        for (int ks = 0; ks < 64; ks += 32) {
            bf16x8 af[4], bq[4];
#pragma unroll
            for (int m = 0; m < 4; ++m)
                af[m] = *(const bf16x8*)&Als[(arow_l + m * 16) * 64 + ks + kfrag];
#pragma unroll
            for (int n = 0; n < 4; ++n)
                bq[n] = *(const bf16x8*)&Bls[(brow_l + n * 16) * 64 + ks + kfrag];
#pragma unroll
            for (int m = 0; m < 4; ++m)
#pragma unroll
                for (int n = 0; n < 4; ++n)
                    acc[m][n] = __builtin_amdgcn_mfma_f32_16x16x32_bf16(
                        af[m], bq[n], acc[m][n], 0, 0, 0);
        }
    }

#pragma unroll
    for (int m = 0; m < 4; ++m) {
        int grow0 = mb + wr * 64 + m * 16 + ((lane >> 4) << 2);
#pragma unroll
        for (int n = 0; n < 4; ++n) {
            int gcol = nb + wc * 64 + n * 16 + (lane & 15);
            float bv = bias[gcol];
#pragma unroll
            for (int q = 0; q < 4; ++q) {
                int grow = grow0 + q;
                float accv[4] = {acc[m][n][0], acc[m][n][1], acc[m][n][2], acc[m][n][3]};
                GEMM_EPI_ELEM()
            }
        }
    }
}

// ---------------------------------------------------------------------------
// MFMA bf16 GEMM, 64x128 tile, 4 waves (1x4). LDS 24KB -> ~6 blocks/CU.
// ---------------------------------------------------------------------------
template <int ACT, int RESID, int SLICE, int OUTBF>
__global__ __launch_bounds__(256) void gemm_mfma64(
    const unsigned short* __restrict__ A,    // [M][K] bf16
    const unsigned short* __restrict__ BT,   // [N][K] bf16
    const float* __restrict__ bias,          // [N]
    const float* __restrict__ resid,         // [M][N] fp32 (if RESID)
    float* __restrict__ outf,                // if !OUTBF
    unsigned short* __restrict__ outb,       // if OUTBF
    int M, int N, int K)
{
    __shared__ unsigned short Als[64 * 64];   // 8KB
    __shared__ unsigned short Bls[128 * 64];  // 16KB

    int tid  = threadIdx.x;
    int lane = tid & 63, w = tid >> 6;
    XCD_SWIZZLE_2D(mb, nb, 64, 128)

    f32x4 acc[4][2];
#pragma unroll
    for (int m = 0; m < 4; ++m)
#pragma unroll
        for (int n = 0; n < 2; ++n)
            acc[m][n] = (f32x4){0.f, 0.f, 0.f, 0.f};

    int srow = w * 8 + (lane >> 3);           // +32 per issue
    int scol = (lane & 7) * 8;
    const unsigned short* abase = A  + (size_t)(mb + srow) * K + scol;
    const unsigned short* bbase = BT + (size_t)(nb + srow) * K + scol;

    int arow_l = lane & 15;                   // + m*16
    int brow_l = w * 32 + (lane & 15);        // + n*16
    int kfrag  = (lane >> 4) * 8;

    for (int kk = 0; kk < K; kk += 64) {
        __syncthreads();
#pragma unroll
        for (int i = 0; i < 2; ++i)
            ASYNC_LDS16(abase + (size_t)(i * 32) * K + kk,
                        (char*)Als + i * 4096 + w * 1024);
#pragma unroll
        for (int i = 0; i < 4; ++i)
            ASYNC_LDS16(bbase + (size_t)(i * 32) * K + kk,
                        (char*)Bls + i * 4096 + w * 1024);
        __syncthreads();
#pragma unroll
        for (int ks = 0; ks < 64; ks += 32) {
            bf16x8 af[4], bq[2];
#pragma unroll
            for (int m = 0; m < 4; ++m)
                af[m] = *(const bf16x8*)&Als[(arow_l + m * 16) * 64 + ks + kfrag];
#pragma unroll
            for (int n = 0; n < 2; ++n)
                bq[n] = *(const bf16x8*)&Bls[(brow_l + n * 16) * 64 + ks + kfrag];
#pragma unroll
            for (int m = 0; m < 4; ++m)
#pragma unroll
                for (int n = 0; n < 2; ++n)
                    acc[m][n] = __builtin_amdgcn_mfma_f32_16x16x32_bf16(
                        af[m], bq[n], acc[m][n], 0, 0, 0);
        }
    }

#pragma unroll
    for (int m = 0; m < 4; ++m) {
        int grow0 = mb + m * 16 + ((lane >> 4) << 2);
#pragma unroll
        for (int n = 0; n < 2; ++n) {
            int gcol = nb + w * 32 + n * 16 + (lane & 15);
            float bv = bias[gcol];
#pragma unroll
            for (int q = 0; q < 4; ++q) {
                int grow = grow0 + q;
                float accv[4] = {acc[m][n][0], acc[m][n][1], acc[m][n][2], acc[m][n][3]};
                GEMM_EPI_ELEM()
            }
        }
    }
}

// ---------------------------------------------------------------------------
// Work table for attn: qt 0..10 whole; qt 11..15 split into two halves.
// ---------------------------------------------------------------------------
__device__ const int ATT_QT[21] = {10,9,8,7,6,5,15,15,14, 4,14,13,13,12, 3,12,11,11, 2,1,0};
__device__ const int ATT_T0[21] = { 0,0,0,0,0,0, 0,10, 0, 0,10, 0, 9, 0, 0, 9, 0, 8, 0,0,0};
__device__ const int ATT_T1[21] = {15,14,13,12,11,10,10,20,10, 9,19, 9,18, 9, 8,17, 8,16, 7,6,5};

// ---------------------------------------------------------------------------
// MFMA fused attention v9 (round-14 best configuration, unchanged).
// ---------------------------------------------------------------------------
__global__ __launch_bounds__(512, 2) void attn_mfma(const unsigned short* __restrict__ qkv,
                                                    const unsigned short* __restrict__ kvctx,
                                                    const float* __restrict__ cabp,
                                                    const int* __restrict__ smpp,
                                                    unsigned short* __restrict__ aout,
                                                    float* __restrict__ Opart,
                                                    float* __restrict__ mlpart)
{
    __shared__ unsigned short Kls[128 * 64];    // 16KB swizzled K tile
    __shared__ unsigned short Vt [64 * 136];    // 17KB V^T [d][k'], stride 136
    __shared__ unsigned short Pls[128 * 136];   // 34KB P [q][k'], stride 136

    int bid = blockIdx.x;
    int j = (bid < 256) ? bid : 503 - (bid - 256);   // desc-asc complementary map
    int rank = j / 24, grp = j % 24;
    int h = grp % 12, b = grp / 12;
    int qt = ATT_QT[rank], t0 = ATT_T0[rank], t1 = ATT_T1[rank];
    bool split = (t1 - t0) < (qt + 5);
    int half = (t0 > 0) ? 1 : 0;

    int tid = threadIdx.x;
    int l = tid & 63, w = tid >> 6;             // wave 0..7
    int g = l >> 4, lc = l & 15;
    float cab = *cabp;
    int   smp = *smpp;
    int qbase = qt * 128;

    // --- Q fragments (pre-scaled by log2e): q = qbase + w*16 + lc ---
    bf16x8 qf0, qf1;
    {
        const unsigned short* qp = qkv + ((size_t)(b * S_ + qbase + w * 16 + lc)) * (3 * D_)
                                       + h * DH_ + g * 8;
        qf0 = *(const bf16x8*)(qp);
        qf1 = *(const bf16x8*)(qp + 32);
#pragma unroll
        for (int i = 0; i < 8; ++i) {
            qf0[i] = (short)f2b(b2f((unsigned short)qf0[i]) * LOG2E_);
            qf1[i] = (short)f2b(b2f((unsigned short)qf1[i]) * LOG2E_);
        }
    }

    // all-ones bf16 B-fragment for the l-sum MFMA (1.0 = 0x3F80)
    bf16x8 vones;
#pragma unroll
    for (int i = 0; i < 8; ++i) vones[i] = (short)0x3F80;

    f32x4 acc[4];
#pragma unroll
    for (int n = 0; n < 4; ++n) acc[n] = (f32x4){0.f, 0.f, 0.f, 0.f};
    f32x4 lacc = (f32x4){0.f, 0.f, 0.f, 0.f};   // row-sum of P, D-layout
    float mrow[4];
#pragma unroll
    for (int e = 0; e < 4; ++e) mrow[e] = -1e30f;

    // staging lane geometry (all loop-invariant)
    int colu = 8 * ((l & 7) ^ (l >> 3));        // pre-swizzled global col (bf16)
    int kvr  = tid >> 3;                        // V k-row 0..63 (+64 second half)
    int d0   = (tid & 7) * 8;                   // V d chunk base
    int dsw  = (tid & 7) << 3;                  // Vt k-swizzle
    int vtrow[8];
#pragma unroll
    for (int jj = 0; jj < 8; ++jj) vtrow[jj] = (d0 + jj) * 136;
    int vo0 = kvr ^ dsw, vo1 = (64 + kvr) ^ dsw;
    int ksw  = (lc & 7) << 3;                   // K-read swizzle (nf-independent)
    int koff0 = (g * 8) ^ ksw, koff1 = (32 + g * 8) ^ ksw;
    us8 vr0, vr1;

#define STAGE_TILE(TT)                                                                   \
    {                                                                                    \
        int kb2 = (TT) * 128;                                                            \
        bool isctx = (kb2 < C_);                                                         \
        _Pragma("unroll")                                                                \
        for (int s2 = 0; s2 < 2; ++s2) {                                                 \
            int s = w * 2 + s2;                                                          \
            int kj = kb2 + s * 8 + (l >> 3);                                             \
            const unsigned short* src = isctx                                            \
                ? kvctx + ((size_t)(b * C_ + kj)) * (2 * D_) + h * DH_ + colu            \
                : qkv + ((size_t)(b * S_ + kj - C_)) * (3 * D_) + D_ + h * DH_ + colu;   \
            ASYNC_LDS16(src, (char*)Kls + s * 1024);                                     \
        }                                                                                \
        int kv0 = kb2 + kvr;                                                             \
        vr0 = *(const us8*)(isctx                                                        \
            ? kvctx + ((size_t)(b * C_ + kv0)) * (2 * D_) + D_ + h * DH_ + d0            \
            : qkv + ((size_t)(b * S_ + kv0 - C_)) * (3 * D_) + 2 * D_ + h * DH_ + d0);   \
        vr1 = *(const us8*)(isctx                                                        \
            ? kvctx + ((size_t)(b * C_ + kv0 + 64)) * (2 * D_) + D_ + h * DH_ + d0       \
            : qkv + ((size_t)(b * S_ + kv0 + 64 - C_)) * (3 * D_) + 2 * D_ + h * DH_ + d0); \
    }

    STAGE_TILE(t0)

    for (int t = t0; t < t1; ++t) {
        int kb = t * 128;
        __syncthreads();   // staging visible; prev PV done reading Vt/Pls

        // ---- V^T scatter: 16 stores, loop-invariant addresses ----
#pragma unroll
        for (int jj = 0; jj < 8; ++jj) {
            Vt[vtrow[jj] + vo0] = vr0[jj];
            Vt[vtrow[jj] + vo1] = vr1[jj];
        }

        // ---- QK^T: S[16q x 128k] per wave (log2 units) ----
        f32x4 s4[8];
#pragma unroll
        for (int nf = 0; nf < 8; ++nf) s4[nf] = (f32x4){0.f, 0.f, 0.f, 0.f};
        __builtin_amdgcn_s_setprio(1);
#pragma unroll
        for (int nf = 0; nf < 8; ++nf) {
            bf16x8 kf0 = *(const bf16x8*)&Kls[(nf * 16 + lc) * 64 + koff0];
            bf16x8 kf1 = *(const bf16x8*)&Kls[(nf * 16 + lc) * 64 + koff1];
            s4[nf] = __builtin_amdgcn_mfma_f32_16x16x32_bf16(qf0, kf0, s4[nf], 0, 0, 0);
            s4[nf] = __builtin_amdgcn_mfma_f32_16x16x32_bf16(qf1, kf1, s4[nf], 0, 0, 0);
        }
        __builtin_amdgcn_s_setprio(0);

        // ---- tile classification (global tile index semantics) ----
        bool edge_t = (t == qt + 4);
        bool diag_t = (kb == qbase) && (smp > 0);
        float tb = (kb < C_) ? cab * LOG2E_ : 0.0f;

        if (edge_t) {
#pragma unroll
            for (int nf = 0; nf < 8; ++nf) {
                int kj = kb + nf * 16 + lc;
#pragma unroll
                for (int e = 0; e < 4; ++e) {
                    int qi = qbase + w * 16 + g * 4 + e;
                    s4[nf][e] = (kj <= qi + C_) ? s4[nf][e] : -100000.0f;
                }
            }
        }
        if (diag_t) {
#pragma unroll
            for (int nf = 0; nf < 8; ++nf) {
                int kj = kb + nf * 16 + lc;
#pragma unroll
                for (int e = 0; e < 4; ++e) {
                    int qi = qbase + w * 16 + g * 4 + e;
                    if (kj == qi) s4[nf][e] = -100000.0f;
                }
            }
        }

        // ---- online softmax (log2 units, raw v_exp_f32, l via MFMA) ----
        float tmax[4], mbase[4];
#pragma unroll
        for (int e = 0; e < 4; ++e) {
            float u0 = fmaxf(fmaxf(s4[0][e], s4[1][e]), fmaxf(s4[2][e], s4[3][e]));
            float u1 = fmaxf(fmaxf(s4[4][e], s4[5][e]), fmaxf(s4[6][e], s4[7][e]));
            tmax[e] = fmaxf(u0, u1);
        }
#pragma unroll
        for (int e = 0; e < 4; ++e) {
            tmax[e] = fmaxf(tmax[e], __shfl_xor(tmax[e], 1));
            tmax[e] = fmaxf(tmax[e], __shfl_xor(tmax[e], 2));
            tmax[e] = fmaxf(tmax[e], __shfl_xor(tmax[e], 4));
            tmax[e] = fmaxf(tmax[e], __shfl_xor(tmax[e], 8));
        }
#pragma unroll
        for (int e = 0; e < 4; ++e) {
            float mn = fmaxf(mrow[e], tmax[e] + tb);
            if (mn > mrow[e]) {                      // defer-rescale (O and l together)
                float sc = fexp2(mrow[e] - mn);
#pragma unroll
                for (int nf2 = 0; nf2 < 4; ++nf2) acc[nf2][e] *= sc;
                lacc[e] *= sc;
                mrow[e] = mn;
            }
            mbase[e] = mrow[e] - tb;
        }
#pragma unroll
        for (int nf = 0; nf < 8; ++nf)
#pragma unroll
            for (int e = 0; e < 4; ++e)
                s4[nf][e] = fexp2(s4[nf][e] - mbase[e]);

        // ---- P -> bf16 via cvt_pk -> swizzled LDS (offset XOR before +base) ----
#pragma unroll
        for (int e = 0; e < 4; ++e) {
            int q = w * 16 + g * 4 + e;
            int qrow = q * 136, qsw = (q & 7) << 3;
#pragma unroll
            for (int a = 0; a < 4; ++a) {
                unsigned int pk;
                asm("v_cvt_pk_bf16_f32 %0, %1, %2"
                    : "=v"(pk) : "v"(s4[2 * a][e]), "v"(s4[2 * a + 1][e]));
                int xk = (a * 32 + lc) ^ qsw;
                Pls[qrow + xk]        = (unsigned short)pk;
                Pls[qrow + (xk ^ 16)] = (unsigned short)(pk >> 16);
            }
        }

        __syncthreads();   // Vt/Pls complete; Kls reads done -> safe to restage

        // ---- stage next tile under PV ----
        if (t + 1 < t1) STAGE_TILE(t + 1)

        // ---- PV: O[16q x 64d] += P @ V ;  l += P @ ones ----
        {
            int qa = w * 16 + lc;
            int qrow = qa * 136, qsw = (qa & 7) << 3;
            __builtin_amdgcn_s_setprio(1);
#pragma unroll
            for (int ks2 = 0; ks2 < 4; ++ks2) {
                bf16x8 pf = *(const bf16x8*)&Pls[qrow + ((ks2 * 32 + g * 8) ^ qsw)];
#pragma unroll
                for (int nf2 = 0; nf2 < 4; ++nf2) {
                    int d = nf2 * 16 + lc;
                    bf16x8 vf = *(const bf16x8*)&Vt[d * 136 +
                                   ((ks2 * 32 + g * 8) ^ (((d >> 3) & 7) << 3))];
                    acc[nf2] = __builtin_amdgcn_mfma_f32_16x16x32_bf16(pf, vf, acc[nf2], 0, 0, 0);
                }
                lacc = __builtin_amdgcn_mfma_f32_16x16x32_bf16(pf, vones, lacc, 0, 0, 0);
            }
            __builtin_amdgcn_s_setprio(0);
        }
    }

    // ---- epilogue: lacc[e] is already the complete row sum (no reduce) ----
    if (!split) {
#pragma unroll
        for (int e = 0; e < 4; ++e) {
            int q = qbase + w * 16 + g * 4 + e;
            float inv = 1.0f / lacc[e];
            unsigned short* dst = &aout[((size_t)(b * S_ + q)) * D_ + h * DH_];
#pragma unroll
            for (int nf2 = 0; nf2 < 4; ++nf2)
                dst[nf2 * 16 + lc] = f2b(acc[nf2][e] * inv);
        }
    } else {
        int rec = ((b * 12 + h) * 5 + (qt - 11)) * 2 + half;
        float* Ob  = Opart + (size_t)rec * 8192;
        float* mlb = mlpart + rec * 256;
#pragma unroll
        for (int e = 0; e < 4; ++e) {
            int row = w * 16 + g * 4 + e;
#pragma unroll
            for (int nf2 = 0; nf2 < 4; ++nf2)
                Ob[row * 64 + nf2 * 16 + lc] = acc[nf2][e];
            if (lc == 0) { mlb[row * 2] = mrow[e]; mlb[row * 2 + 1] = lacc[e]; }
        }
    }
#undef STAGE_TILE
}

// ---------------------------------------------------------------------------
// Merge split-KV halves (log2 units): c_i = 2^(m_i - m) via v_exp_f32.
// ---------------------------------------------------------------------------
__global__ __launch_bounds__(256) void attn_merge(const float* __restrict__ Opart,
                                                  const float* __restrict__ mlpart,
                                                  unsigned short* __restrict__ aout)
{
    int rec = blockIdx.x;                 // (b*12+h)*5 + qidx
    int qidx = rec % 5;
    int bh = rec / 5;
    int h = bh % 12, b = bh / 12;
    int qt = 11 + qidx;
    int row = threadIdx.x >> 1, dbase = (threadIdx.x & 1) * 32;

    const float* O0  = Opart + ((size_t)(rec * 2 + 0)) * 8192 + row * 64 + dbase;
    const float* O1  = Opart + ((size_t)(rec * 2 + 1)) * 8192 + row * 64 + dbase;
    const float* ml0 = mlpart + (rec * 2 + 0) * 256 + row * 2;
    const float* ml1 = mlpart + (rec * 2 + 1) * 256 + row * 2;
    float m0 = ml0[0], l0 = ml0[1];
    float m1 = ml1[0], l1 = ml1[1];
    float m  = fmaxf(m0, m1);
    float c0 = fexp2(m0 - m), c1 = fexp2(m1 - m);
    float inv = 1.0f / (l0 * c0 + l1 * c1);

    int q = qt * 128 + row;
    unsigned short* dst = &aout[((size_t)(b * S_ + q)) * D_ + h * DH_ + dbase];
#pragma unroll
    for (int jj = 0; jj < 32; ++jj)
        dst[jj] = f2b((O0[jj] * c0 + O1[jj] * c1) * inv);
}

// ---------------------------------------------------------------------------
extern "C" void kernel_launch(void* const* d_in, const int* in_sizes, int n_in,
                              void* d_out, int out_size, void* d_ws, size_t ws_size,
                              hipStream_t stream)
{
    const float* x     = (const float*)d_in[0];
    const float* ctx   = (const float*)d_in[1];
    const float* ln1g  = (const float*)d_in[2];
    const float* ln1b  = (const float*)d_in[3];
    const float* Wattn = (const float*)d_in[4];
    const float* battn = (const float*)d_in[5];
    const float* Wref  = (const float*)d_in[6];
    const float* bref  = (const float*)d_in[7];
    const float* Wproj = (const float*)d_in[8];
    const float* bproj = (const float*)d_in[9];
    const float* ln2g  = (const float*)d_in[10];
    const float* ln2b  = (const float*)d_in[11];
    const float* W1    = (const float*)d_in[12];
    const float* b1    = (const float*)d_in[13];
    const float* W2    = (const float*)d_in[14];
    const float* b2    = (const float*)d_in[15];
    const float* cab   = (const float*)d_in[16];
    const int*   smp   = (const int*)d_in[17];
    float* out = (float*)d_out;

    // ---- workspace layout (float units) ----
    float* ws = (float*)d_ws;
    unsigned short* qkvb   = (unsigned short*)(ws + 0);          // 4096x2304 bf16 (steps 2-4)
    unsigned short* ff1b   = (unsigned short*)(ws + 0);          // 4096x3072 bf16 (steps 7-8)
    unsigned short* kvctxb = (unsigned short*)(ws + 4718592);    // 1024x1536 bf16
    unsigned short* attnb  = (unsigned short*)(ws + 5505024);    // 4096x768 bf16 (ends 7077888)
    unsigned short* hb     = (unsigned short*)(ws + 7077888);    // 4096x768 bf16 (ends 8650752)
    float*          x1     = ws + 8650752;                       // 4096x768 fp32 (ends 11796480)
    // attn split partials overlay hb+x1 region (dead during attention):
    float*          Opart  = ws + 7077888;                       // 3,932,160 fl (ends 11010048)
    float*          mlpart = ws + 11010048;                      // 61,440 fl  (ends 11071488)
    unsigned short* ctxb   = (unsigned short*)(ws + 11796480);   // 1024x768 bf16 (ends 12189696)
    unsigned short* wts    = (unsigned short*)(ws + 12189696);   // bf16 weights
    unsigned short* wattnT = wts;                                // 2304x768
    unsigned short* wrefT  = wts + 1769472;                      // 1536x768
    unsigned short* wprojT = wts + 2949120;                      // 768x768
    unsigned short* w1T    = wts + 3538944;                      // 3072x768
    unsigned short* w2T    = wts + 5898240;                      // 768x3072

    // 0. fused prep: 5 transposes (vectorized) + ctx convert + LN1
    wprep<<<12928, 256, 0, stream>>>(Wattn, Wref, Wproj, W1, W2, ctx, x, ln1g, ln1b,
                                     wattnT, wrefT, wprojT, w1T, w2T, ctxb, hb);
    // 1. qkv + kvctx fused GEMM (672 blocks)
    gemm_qkv_ctx<<<672, 256, 0, stream>>>(hb, wattnT, battn, qkvb,
                                          ctxb, wrefT, bref, kvctxb);
    // 2. attention (split-KV balanced, l-via-MFMA) + merge
    attn_mfma<<<504, 512, 0, stream>>>(qkvb, kvctxb, cab, smp, attnb, Opart, mlpart);
    attn_merge<<<120, 256, 0, stream>>>(Opart, mlpart, attnb);
    // 3. x1 = x + attn @ Wproj + bproj  (64x128 tile, 384 blocks)
    gemm_mfma64<0, 1, 0, 0><<<dim3(6, 64), 256, 0, stream>>>(
        attnb, wprojT, bproj, x, x1, nullptr, 4096, 768, 768);
    // 4. h = LN2(x1)
    ln_kernel<<<B_ * S_, 256, 0, stream>>>(x1, ln2g, ln2b, hb);
    // 5. ff1 = silu(h @ W1 + b1)   (128x128 tile, 768 blocks)
    gemm_mfma<1, 0, 0, 1><<<dim3(24, 32), 256, 0, stream>>>(
        hb, w1T, b1, nullptr, nullptr, ff1b, 4096, 3072, 768);
    // 6. out = slice(x1 + ff1 @ W2 + b2)  (64x128 tile, 384 blocks)
    gemm_mfma64<0, 1, 1, 0><<<dim3(6, 64), 256, 0, stream>>>(
        ff1b, w2T, b2, x1, out, nullptr, 4096, 768, 3072);
}

// Round 17
// 243.064 us; speedup vs baseline: 1.0735x; 1.0675x over previous
//
#include <hip/hip_runtime.h>
#include <hip/hip_bf16.h>
#include <math.h>

// Problem constants
#define B_   2
#define S_   2048
#define C_   512
#define D_   768
#define H_   12
#define DH_  64
#define DFF_ 3072
#define NS_  (C_ + S_)   // 2560
#define LOG2E_ 1.44269504f

typedef __attribute__((ext_vector_type(8))) short          bf16x8;
typedef __attribute__((ext_vector_type(4))) float          f32x4;
typedef __attribute__((ext_vector_type(8))) unsigned short us8;
typedef __attribute__((ext_vector_type(4))) unsigned short us4;

static __device__ __forceinline__ unsigned short f2b(float f) {
    unsigned int u = __float_as_uint(f);
    unsigned int r = (u + 0x7FFFu + ((u >> 16) & 1u)) >> 16;   // RNE
    return (unsigned short)r;
}
static __device__ __forceinline__ float b2f(unsigned short u) {
    return __uint_as_float(((unsigned int)u) << 16);
}
// raw v_exp_f32: D = 2^S0 (1 instruction; exp2f libm path is ~6-8)
static __device__ __forceinline__ float fexp2(float x) {
    float r;
    asm("v_exp_f32 %0, %1" : "=v"(r) : "v"(x));
    return r;
}

// async global->LDS, 16B per lane; lptr must be wave-uniform base
#define ASYNC_LDS16(gp, lp)                                                     \
    __builtin_amdgcn_global_load_lds(                                           \
        (const __attribute__((address_space(1))) void*)(gp),                    \
        (__attribute__((address_space(3))) void*)(lp), 16, 0, 0)

// XCD-chunked bijective block remap (requires nwg % 8 == 0; all call sites hold)
#define XCD_SWIZZLE_2D(MB, NB, TM, TN)                                          \
    int nwg_ = gridDim.x * gridDim.y;                                           \
    int bid_ = blockIdx.y * gridDim.x + blockIdx.x;                             \
    int q8_  = nwg_ >> 3;                                                       \
    int swz_ = (bid_ & 7) * q8_ + (bid_ >> 3);                                  \
    int MB = (swz_ / gridDim.x) * (TM);                                         \
    int NB = (swz_ % gridDim.x) * (TN);

// ---------------------------------------------------------------------------
// LayerNorm over D=768 -> bf16 out. One block (256 threads) per row.
// ---------------------------------------------------------------------------
__global__ __launch_bounds__(256) void ln_kernel(const float* __restrict__ in,
                                                 const float* __restrict__ g,
                                                 const float* __restrict__ bta,
                                                 unsigned short* __restrict__ out)
{
    int row = blockIdx.x;
    int tid = threadIdx.x;
    const float* x = in + (size_t)row * D_;
    float v0 = x[tid], v1 = x[tid + 256], v2 = x[tid + 512];
    float s  = v0 + v1 + v2;
    float s2 = v0 * v0 + v1 * v1 + v2 * v2;
#pragma unroll
    for (int off = 32; off >= 1; off >>= 1) {
        s  += __shfl_down(s,  off, 64);
        s2 += __shfl_down(s2, off, 64);
    }
    __shared__ float sh[8];
    int lane = tid & 63, wv = tid >> 6;
    if (lane == 0) { sh[wv] = s; sh[4 + wv] = s2; }
    __syncthreads();
    s  = sh[0] + sh[1] + sh[2] + sh[3];
    s2 = sh[4] + sh[5] + sh[6] + sh[7];
    float mu   = s * (1.0f / D_);
    float var  = s2 * (1.0f / D_) - mu * mu;
    float rstd = rsqrtf(var + 1e-5f);
    unsigned short* o = out + (size_t)row * D_;
    o[tid]       = f2b((v0 - mu) * rstd * g[tid]       + bta[tid]);
    o[tid + 256] = f2b((v1 - mu) * rstd * g[tid + 256] + bta[tid + 256]);
    o[tid + 512] = f2b((v2 - mu) * rstd * g[tid + 512] + bta[tid + 512]);
}

// ---------------------------------------------------------------------------
// Fused prep: 5 weight transposes (vectorized) + ctx convert + LN1.
// ---------------------------------------------------------------------------
__global__ __launch_bounds__(256) void wprep(
    const float* __restrict__ Wattn, const float* __restrict__ Wref,
    const float* __restrict__ Wproj, const float* __restrict__ W1,
    const float* __restrict__ W2,    const float* __restrict__ ctx,
    const float* __restrict__ x,     const float* __restrict__ ln1g,
    const float* __restrict__ ln1b,
    unsigned short* __restrict__ wattnT, unsigned short* __restrict__ wrefT,
    unsigned short* __restrict__ wprojT, unsigned short* __restrict__ w1T,
    unsigned short* __restrict__ w2T,    unsigned short* __restrict__ ctxb,
    unsigned short* __restrict__ hb)
{
    __shared__ float t[32][33];
    __shared__ float sh[8];
    int bid = blockIdx.x;
    int tid = threadIdx.x;

    if (bid >= 8832) {   // ---- LN1 segment ----
        int row = bid - 8832;
        const float* xr = x + (size_t)row * D_;
        float v0 = xr[tid], v1 = xr[tid + 256], v2 = xr[tid + 512];
        float s  = v0 + v1 + v2;
        float s2 = v0 * v0 + v1 * v1 + v2 * v2;
#pragma unroll
        for (int off = 32; off >= 1; off >>= 1) {
            s  += __shfl_down(s,  off, 64);
            s2 += __shfl_down(s2, off, 64);
        }
        int lane = tid & 63, wv = tid >> 6;
        if (lane == 0) { sh[wv] = s; sh[4 + wv] = s2; }
        __syncthreads();
        s  = sh[0] + sh[1] + sh[2] + sh[3];
        s2 = sh[4] + sh[5] + sh[6] + sh[7];
        float mu   = s * (1.0f / D_);
        float var  = s2 * (1.0f / D_) - mu * mu;
        float rstd = rsqrtf(var + 1e-5f);
        unsigned short* o = hb + (size_t)row * D_;
        o[tid]       = f2b((v0 - mu) * rstd * ln1g[tid]       + ln1b[tid]);
        o[tid + 256] = f2b((v1 - mu) * rstd * ln1g[tid + 256] + ln1b[tid + 256]);
        o[tid + 512] = f2b((v2 - mu) * rstd * ln1g[tid + 512] + ln1b[tid + 512]);
        return;
    }
    if (bid >= 8064) {   // ---- ctx convert ----
        int i = (bid - 8064) * 256 + tid;
        float4 v = ((const float4*)ctx)[i];
        us4 o = { f2b(v.x), f2b(v.y), f2b(v.z), f2b(v.w) };
        ((us4*)ctxb)[i] = o;
        return;
    }
    // ---- weight transpose segment (vectorized) ----
    const float* in; unsigned short* outp; int K, N, nt;
    if (bid < 1728)      {             in = Wattn; outp = wattnT; K = 768;  N = 2304; nt = 72; }
    else if (bid < 2880) { bid -= 1728; in = Wref;  outp = wrefT;  K = 768;  N = 1536; nt = 48; }
    else if (bid < 3456) { bid -= 2880; in = Wproj; outp = wprojT; K = 768;  N = 768;  nt = 24; }
    else if (bid < 5760) { bid -= 3456; in = W1;    outp = w1T;    K = 768;  N = 3072; nt = 96; }
    else                 { bid -= 5760; in = W2;    outp = w2T;    K = 3072; N = 768;  nt = 24; }
    int n0 = (bid % nt) * 32, k0 = (bid / nt) * 32;
    int r  = tid >> 3;            // 0..31
    int c4 = (tid & 7) * 4;       // 0,4,..,28
    float4 v4 = *(const float4*)&in[(size_t)(k0 + r) * N + n0 + c4];
    t[r][c4]     = v4.x;
    t[r][c4 + 1] = v4.y;
    t[r][c4 + 2] = v4.z;
    t[r][c4 + 3] = v4.w;
    __syncthreads();
    us4 ov = { f2b(t[c4][r]), f2b(t[c4 + 1][r]), f2b(t[c4 + 2][r]), f2b(t[c4 + 3][r]) };
    *(us4*)&outp[(size_t)(n0 + r) * K + k0 + c4] = ov;
}

// ---------------------------------------------------------------------------
// Shared GEMM epilogue
// ---------------------------------------------------------------------------
#define GEMM_EPI_ELEM()                                                         \
    {                                                                           \
        float v = accv[q] + bv;                                                 \
        if (ACT) v = v / (1.0f + __expf(-v));                                   \
        if (RESID) v += resid[(size_t)grow * N + gcol];                         \
        if (OUTBF) {                                                            \
            outb[(size_t)grow * N + gcol] = f2b(v);                             \
        } else if (SLICE) {                                                     \
            int bb = grow >> 11, ss = grow & 2047;                              \
            if (ss > 0)                                                         \
                outf[((size_t)(bb * 2047 + ss - 1)) * N + gcol] = v;            \
        } else {                                                                \
            outf[(size_t)grow * N + gcol] = v;                                  \
        }                                                                       \
    }

// ---------------------------------------------------------------------------
// Fused qkv + kvctx GEMM (both 128x128 tile, OUTBF, K=768). 672 blocks.
// ---------------------------------------------------------------------------
__global__ __launch_bounds__(256) void gemm_qkv_ctx(
    const unsigned short* __restrict__ hb, const unsigned short* __restrict__ wattnT,
    const float* __restrict__ battn, unsigned short* __restrict__ qkvb,
    const unsigned short* __restrict__ ctxb, const unsigned short* __restrict__ wrefT,
    const float* __restrict__ bref, unsigned short* __restrict__ kvctxb)
{
    __shared__ unsigned short Als[128 * 64];
    __shared__ unsigned short Bls[128 * 64];

    int bid = blockIdx.x;
    const unsigned short *A, *BT; const float* bias; unsigned short* outb;
    int N, gx, nblk, sb;
    if (bid < 576) { A = hb;   BT = wattnT; bias = battn; outb = qkvb;   N = 2304; gx = 18; nblk = 576; sb = bid; }
    else           { A = ctxb; BT = wrefT;  bias = bref;  outb = kvctxb; N = 1536; gx = 12; nblk = 96;  sb = bid - 576; }
    int swz = (sb & 7) * (nblk >> 3) + (sb >> 3);
    int mb = (swz / gx) * 128, nb = (swz % gx) * 128;
    const int K = 768;

    int tid  = threadIdx.x;
    int lane = tid & 63, w = tid >> 6;
    int wr = w >> 1, wc = w & 1;

    f32x4 acc[4][4];
#pragma unroll
    for (int m = 0; m < 4; ++m)
#pragma unroll
        for (int n = 0; n < 4; ++n)
            acc[m][n] = (f32x4){0.f, 0.f, 0.f, 0.f};

    int srow = w * 32 + (lane >> 3);
    int scol = (lane & 7) * 8;
    const unsigned short* abase = A  + (size_t)(mb + srow) * K + scol;
    const unsigned short* bbase = BT + (size_t)(nb + srow) * K + scol;

    int arow_l = wr * 64 + (lane & 15);
    int brow_l = wc * 64 + (lane & 15);
    int kfrag  = (lane >> 4) * 8;

    for (int kk = 0; kk < K; kk += 64) {
        __syncthreads();
#pragma unroll
        for (int i = 0; i < 4; ++i) {
            ASYNC_LDS16(abase + (size_t)(i * 8) * K + kk,
                        (char*)Als + (w * 32 + i * 8) * 128);
            ASYNC_LDS16(bbase + (size_t)(i * 8) * K + kk,
                        (char*)Bls + (w * 32 + i * 8) * 128);
        }
        __syncthreads();
#pragma unroll
        for (int ks = 0; ks < 64; ks += 32) {
            bf16x8 af[4], bq[4];
#pragma unroll
            for (int m = 0; m < 4; ++m)
                af[m] = *(const bf16x8*)&Als[(arow_l + m * 16) * 64 + ks + kfrag];
#pragma unroll
            for (int n = 0; n < 4; ++n)
                bq[n] = *(const bf16x8*)&Bls[(brow_l + n * 16) * 64 + ks + kfrag];
#pragma unroll
            for (int m = 0; m < 4; ++m)
#pragma unroll
                for (int n = 0; n < 4; ++n)
                    acc[m][n] = __builtin_amdgcn_mfma_f32_16x16x32_bf16(
                        af[m], bq[n], acc[m][n], 0, 0, 0);
        }
    }

#pragma unroll
    for (int m = 0; m < 4; ++m) {
        int grow0 = mb + wr * 64 + m * 16 + ((lane >> 4) << 2);
#pragma unroll
        for (int n = 0; n < 4; ++n) {
            int gcol = nb + wc * 64 + n * 16 + (lane & 15);
            float bv = bias[gcol];
#pragma unroll
            for (int q = 0; q < 4; ++q) {
                int grow = grow0 + q;
                outb[(size_t)grow * N + gcol] = f2b(acc[m][n][q] + bv);
            }
        }
    }
}

// ---------------------------------------------------------------------------
// MFMA bf16 GEMM (m97 structure): 128x128 tile, 4 waves (2x2), BK=64.
// ---------------------------------------------------------------------------
template <int ACT, int RESID, int SLICE, int OUTBF>
__global__ __launch_bounds__(256) void gemm_mfma(
    const unsigned short* __restrict__ A,    // [M][K] bf16
    const unsigned short* __restrict__ BT,   // [N][K] bf16
    const float* __restrict__ bias,          // [N]
    const float* __restrict__ resid,         // [M][N] fp32 (if RESID)
    float* __restrict__ outf,                // if !OUTBF
    unsigned short* __restrict__ outb,       // if OUTBF
    int M, int N, int K)
{
    __shared__ unsigned short Als[128 * 64];
    __shared__ unsigned short Bls[128 * 64];

    int tid  = threadIdx.x;
    int lane = tid & 63, w = tid >> 6;
    XCD_SWIZZLE_2D(mb, nb, 128, 128)
    int wr = w >> 1, wc = w & 1;

    f32x4 acc[4][4];
#pragma unroll
    for (int m = 0; m < 4; ++m)
#pragma unroll
        for (int n = 0; n < 4; ++n)
            acc[m][n] = (f32x4){0.f, 0.f, 0.f, 0.f};

    int srow = w * 32 + (lane >> 3);
    int scol = (lane & 7) * 8;
    const unsigned short* abase = A  + (size_t)(mb + srow) * K + scol;
    const unsigned short* bbase = BT + (size_t)(nb + srow) * K + scol;

    int arow_l = wr * 64 + (lane & 15);
    int brow_l = wc * 64 + (lane & 15);
    int kfrag  = (lane >> 4) * 8;

    for (int kk = 0; kk < K; kk += 64) {
        __syncthreads();
#pragma unroll
        for (int i = 0; i < 4; ++i) {
            ASYNC_LDS16(abase + (size_t)(i * 8) * K + kk,
                        (char*)Als + (w * 32 + i * 8) * 128);
            ASYNC_LDS16(bbase + (size_t)(i * 8) * K + kk,
                        (char*)Bls + (w * 32 + i * 8) * 128);
        }
        __syncthreads();
#pragma unroll
        for (int ks = 0; ks < 64; ks += 32) {
            bf16x8 af[4], bq[4];
#pragma unroll
            for (int m = 0; m < 4; ++m)
                af[m] = *(const bf16x8*)&Als[(arow_l + m * 16) * 64 + ks + kfrag];
#pragma unroll
            for (int n = 0; n < 4; ++n)
                bq[n] = *(const bf16x8*)&Bls[(brow_l + n * 16) * 64 + ks + kfrag];
#pragma unroll
            for (int m = 0; m < 4; ++m)
#pragma unroll
                for (int n = 0; n < 4; ++n)
                    acc[m][n] = __builtin_amdgcn_mfma_f32_16x16x32_bf16(
                        af[m], bq[n], acc[m][n], 0, 0, 0);
        }
    }

#pragma unroll
    for (int m = 0; m < 4; ++m) {
        int grow0 = mb + wr * 64 + m * 16 + ((lane >> 4) << 2);
#pragma unroll
        for (int n = 0; n < 4; ++n) {
            int gcol = nb + wc * 64 + n * 16 + (lane & 15);
            float bv = bias[gcol];
#pragma unroll
            for (int q = 0; q < 4; ++q) {
                int grow = grow0 + q;
                float accv[4] = {acc[m][n][0], acc[m][n][1], acc[m][n][2], acc[m][n][3]};
                GEMM_EPI_ELEM()
            }
        }
    }
}

// ---------------------------------------------------------------------------
// MFMA bf16 GEMM, 32x128 tile, 4 waves (1x4: wave w = 32 rows x cols w*32..+31).
// LDS 20KB; 768-block grids for proj/ff2 -> 3 blocks/CU even, 12 waves/CU.
// ---------------------------------------------------------------------------
template <int ACT, int RESID, int SLICE, int OUTBF>
__global__ __launch_bounds__(256) void gemm_mfma32(
    const unsigned short* __restrict__ A,    // [M][K] bf16
    const unsigned short* __restrict__ BT,   // [N][K] bf16
    const float* __restrict__ bias,          // [N]
    const float* __restrict__ resid,         // [M][N] fp32 (if RESID)
    float* __restrict__ outf,                // if !OUTBF
    unsigned short* __restrict__ outb,       // if OUTBF
    int M, int N, int K)
{
    __shared__ unsigned short Als[32 * 64];   // 4KB
    __shared__ unsigned short Bls[128 * 64];  // 16KB

    int tid  = threadIdx.x;
    int lane = tid & 63, w = tid >> 6;
    XCD_SWIZZLE_2D(mb, nb, 32, 128)

    f32x4 acc[2][2];
#pragma unroll
    for (int m = 0; m < 2; ++m)
#pragma unroll
        for (int n = 0; n < 2; ++n)
            acc[m][n] = (f32x4){0.f, 0.f, 0.f, 0.f};

    int srow = w * 8 + (lane >> 3);           // A: 8 rows/wave, 1 issue
    int scol = (lane & 7) * 8;
    const unsigned short* abase = A  + (size_t)(mb + srow) * K + scol;
    const unsigned short* bbase = BT + (size_t)(nb + srow) * K + scol;   // +32/issue

    int arow_l = lane & 15;                   // + m*16
    int brow_l = w * 32 + (lane & 15);        // + n*16
    int kfrag  = (lane >> 4) * 8;

    for (int kk = 0; kk < K; kk += 64) {
        __syncthreads();
        ASYNC_LDS16(abase + kk, (char*)Als + w * 1024);
#pragma unroll
        for (int i = 0; i < 4; ++i)
            ASYNC_LDS16(bbase + (size_t)(i * 32) * K + kk,
                        (char*)Bls + i * 4096 + w * 1024);
        __syncthreads();
#pragma unroll
        for (int ks = 0; ks < 64; ks += 32) {
            bf16x8 af[2], bq[2];
#pragma unroll
            for (int m = 0; m < 2; ++m)
                af[m] = *(const bf16x8*)&Als[(arow_l + m * 16) * 64 + ks + kfrag];
#pragma unroll
            for (int n = 0; n < 2; ++n)
                bq[n] = *(const bf16x8*)&Bls[(brow_l + n * 16) * 64 + ks + kfrag];
#pragma unroll
            for (int m = 0; m < 2; ++m)
#pragma unroll
                for (int n = 0; n < 2; ++n)
                    acc[m][n] = __builtin_amdgcn_mfma_f32_16x16x32_bf16(
                        af[m], bq[n], acc[m][n], 0, 0, 0);
        }
    }

#pragma unroll
    for (int m = 0; m < 2; ++m) {
        int grow0 = mb + m * 16 + ((lane >> 4) << 2);
#pragma unroll
        for (int n = 0; n < 2; ++n) {
            int gcol = nb + w * 32 + n * 16 + (lane & 15);
            float bv = bias[gcol];
#pragma unroll
            for (int q = 0; q < 4; ++q) {
                int grow = grow0 + q;
                float accv[4] = {acc[m][n][0], acc[m][n][1], acc[m][n][2], acc[m][n][3]};
                GEMM_EPI_ELEM()
            }
        }
    }
}

// ---------------------------------------------------------------------------
// Work table for attn: qt 0..10 whole; qt 11..15 split into two halves.
// ---------------------------------------------------------------------------
__device__ const int ATT_QT[21] = {10,9,8,7,6,5,15,15,14, 4,14,13,13,12, 3,12,11,11, 2,1,0};
__device__ const int ATT_T0[21] = { 0,0,0,0,0,0, 0,10, 0, 0,10, 0, 9, 0, 0, 9, 0, 8, 0,0,0};
__device__ const int ATT_T1[21] = {15,14,13,12,11,10,10,20,10, 9,19, 9,18, 9, 8,17, 8,16, 7,6,5};

// ---------------------------------------------------------------------------
// MFMA fused attention v9 (round-14 best configuration, unchanged).
// ---------------------------------------------------------------------------
__global__ __launch_bounds__(512, 2) void attn_mfma(const unsigned short* __restrict__ qkv,
                                                    const unsigned short* __restrict__ kvctx,
                                                    const float* __restrict__ cabp,
                                                    const int* __restrict__ smpp,
                                                    unsigned short* __restrict__ aout,
                                                    float* __restrict__ Opart,
                                                    float* __restrict__ mlpart)
{
    __shared__ unsigned short Kls[128 * 64];    // 16KB swizzled K tile
    __shared__ unsigned short Vt [64 * 136];    // 17KB V^T [d][k'], stride 136
    __shared__ unsigned short Pls[128 * 136];   // 34KB P [q][k'], stride 136

    int bid = blockIdx.x;
    int j = (bid < 256) ? bid : 503 - (bid - 256);   // desc-asc complementary map
    int rank = j / 24, grp = j % 24;
    int h = grp % 12, b = grp / 12;
    int qt = ATT_QT[rank], t0 = ATT_T0[rank], t1 = ATT_T1[rank];
    bool split = (t1 - t0) < (qt + 5);
    int half = (t0 > 0) ? 1 : 0;

    int tid = threadIdx.x;
    int l = tid & 63, w = tid >> 6;             // wave 0..7
    int g = l >> 4, lc = l & 15;
    float cab = *cabp;
    int   smp = *smpp;
    int qbase = qt * 128;

    // --- Q fragments (pre-scaled by log2e): q = qbase + w*16 + lc ---
    bf16x8 qf0, qf1;
    {
        const unsigned short* qp = qkv + ((size_t)(b * S_ + qbase + w * 16 + lc)) * (3 * D_)
                                       + h * DH_ + g * 8;
        qf0 = *(const bf16x8*)(qp);
        qf1 = *(const bf16x8*)(qp + 32);
#pragma unroll
        for (int i = 0; i < 8; ++i) {
            qf0[i] = (short)f2b(b2f((unsigned short)qf0[i]) * LOG2E_);
            qf1[i] = (short)f2b(b2f((unsigned short)qf1[i]) * LOG2E_);
        }
    }

    // all-ones bf16 B-fragment for the l-sum MFMA (1.0 = 0x3F80)
    bf16x8 vones;
#pragma unroll
    for (int i = 0; i < 8; ++i) vones[i] = (short)0x3F80;

    f32x4 acc[4];
#pragma unroll
    for (int n = 0; n < 4; ++n) acc[n] = (f32x4){0.f, 0.f, 0.f, 0.f};
    f32x4 lacc = (f32x4){0.f, 0.f, 0.f, 0.f};   // row-sum of P, D-layout
    float mrow[4];
#pragma unroll
    for (int e = 0; e < 4; ++e) mrow[e] = -1e30f;

    // staging lane geometry (all loop-invariant)
    int colu = 8 * ((l & 7) ^ (l >> 3));        // pre-swizzled global col (bf16)
    int kvr  = tid >> 3;                        // V k-row 0..63 (+64 second half)
    int d0   = (tid & 7) * 8;                   // V d chunk base
    int dsw  = (tid & 7) << 3;                  // Vt k-swizzle
    int vtrow[8];
#pragma unroll
    for (int jj = 0; jj < 8; ++jj) vtrow[jj] = (d0 + jj) * 136;
    int vo0 = kvr ^ dsw, vo1 = (64 + kvr) ^ dsw;
    int ksw  = (lc & 7) << 3;                   // K-read swizzle (nf-independent)
    int koff0 = (g * 8) ^ ksw, koff1 = (32 + g * 8) ^ ksw;
    us8 vr0, vr1;

#define STAGE_TILE(TT)                                                                   \
    {                                                                                    \
        int kb2 = (TT) * 128;                                                            \
        bool isctx = (kb2 < C_);                                                         \
        _Pragma("unroll")                                                                \
        for (int s2 = 0; s2 < 2; ++s2) {                                                 \
            int s = w * 2 + s2;                                                          \
            int kj = kb2 + s * 8 + (l >> 3);                                             \
            const unsigned short* src = isctx                                            \
                ? kvctx + ((size_t)(b * C_ + kj)) * (2 * D_) + h * DH_ + colu            \
                : qkv + ((size_t)(b * S_ + kj - C_)) * (3 * D_) + D_ + h * DH_ + colu;   \
            ASYNC_LDS16(src, (char*)Kls + s * 1024);                                     \
        }                                                                                \
        int kv0 = kb2 + kvr;                                                             \
        vr0 = *(const us8*)(isctx                                                        \
            ? kvctx + ((size_t)(b * C_ + kv0)) * (2 * D_) + D_ + h * DH_ + d0            \
            : qkv + ((size_t)(b * S_ + kv0 - C_)) * (3 * D_) + 2 * D_ + h * DH_ + d0);   \
        vr1 = *(const us8*)(isctx                                                        \
            ? kvctx + ((size_t)(b * C_ + kv0 + 64)) * (2 * D_) + D_ + h * DH_ + d0       \
            : qkv + ((size_t)(b * S_ + kv0 + 64 - C_)) * (3 * D_) + 2 * D_ + h * DH_ + d0); \
    }

    STAGE_TILE(t0)

    for (int t = t0; t < t1; ++t) {
        int kb = t * 128;
        __syncthreads();   // staging visible; prev PV done reading Vt/Pls

        // ---- V^T scatter: 16 stores, loop-invariant addresses ----
#pragma unroll
        for (int jj = 0; jj < 8; ++jj) {
            Vt[vtrow[jj] + vo0] = vr0[jj];
            Vt[vtrow[jj] + vo1] = vr1[jj];
        }

        // ---- QK^T: S[16q x 128k] per wave (log2 units) ----
        f32x4 s4[8];
#pragma unroll
        for (int nf = 0; nf < 8; ++nf) s4[nf] = (f32x4){0.f, 0.f, 0.f, 0.f};
        __builtin_amdgcn_s_setprio(1);
#pragma unroll
        for (int nf = 0; nf < 8; ++nf) {
            bf16x8 kf0 = *(const bf16x8*)&Kls[(nf * 16 + lc) * 64 + koff0];
            bf16x8 kf1 = *(const bf16x8*)&Kls[(nf * 16 + lc) * 64 + koff1];
            s4[nf] = __builtin_amdgcn_mfma_f32_16x16x32_bf16(qf0, kf0, s4[nf], 0, 0, 0);
            s4[nf] = __builtin_amdgcn_mfma_f32_16x16x32_bf16(qf1, kf1, s4[nf], 0, 0, 0);
        }
        __builtin_amdgcn_s_setprio(0);

        // ---- tile classification (global tile index semantics) ----
        bool edge_t = (t == qt + 4);
        bool diag_t = (kb == qbase) && (smp > 0);
        float tb = (kb < C_) ? cab * LOG2E_ : 0.0f;

        if (edge_t) {
#pragma unroll
            for (int nf = 0; nf < 8; ++nf) {
                int kj = kb + nf * 16 + lc;
#pragma unroll
                for (int e = 0; e < 4; ++e) {
                    int qi = qbase + w * 16 + g * 4 + e;
                    s4[nf][e] = (kj <= qi + C_) ? s4[nf][e] : -100000.0f;
                }
            }
        }
        if (diag_t) {
#pragma unroll
            for (int nf = 0; nf < 8; ++nf) {
                int kj = kb + nf * 16 + lc;
#pragma unroll
                for (int e = 0; e < 4; ++e) {
                    int qi = qbase + w * 16 + g * 4 + e;
                    if (kj == qi) s4[nf][e] = -100000.0f;
                }
            }
        }

        // ---- online softmax (log2 units, raw v_exp_f32, l via MFMA) ----
        float tmax[4], mbase[4];
#pragma unroll
        for (int e = 0; e < 4; ++e) {
            float u0 = fmaxf(fmaxf(s4[0][e], s4[1][e]), fmaxf(s4[2][e], s4[3][e]));
            float u1 = fmaxf(fmaxf(s4[4][e], s4[5][e]), fmaxf(s4[6][e], s4[7][e]));
            tmax[e] = fmaxf(u0, u1);
        }
#pragma unroll
        for (int e = 0; e < 4; ++e) {
            tmax[e] = fmaxf(tmax[e], __shfl_xor(tmax[e], 1));
            tmax[e] = fmaxf(tmax[e], __shfl_xor(tmax[e], 2));
            tmax[e] = fmaxf(tmax[e], __shfl_xor(tmax[e], 4));
            tmax[e] = fmaxf(tmax[e], __shfl_xor(tmax[e], 8));
        }
#pragma unroll
        for (int e = 0; e < 4; ++e) {
            float mn = fmaxf(mrow[e], tmax[e] + tb);
            if (mn > mrow[e]) {                      // defer-rescale (O and l together)
                float sc = fexp2(mrow[e] - mn);
#pragma unroll
                for (int nf2 = 0; nf2 < 4; ++nf2) acc[nf2][e] *= sc;
                lacc[e] *= sc;
                mrow[e] = mn;
            }
            mbase[e] = mrow[e] - tb;
        }
#pragma unroll
        for (int nf = 0; nf < 8; ++nf)
#pragma unroll
            for (int e = 0; e < 4; ++e)
                s4[nf][e] = fexp2(s4[nf][e] - mbase[e]);

        // ---- P -> bf16 via cvt_pk -> swizzled LDS (offset XOR before +base) ----
#pragma unroll
        for (int e = 0; e < 4; ++e) {
            int q = w * 16 + g * 4 + e;
            int qrow = q * 136, qsw = (q & 7) << 3;
#pragma unroll
            for (int a = 0; a < 4; ++a) {
                unsigned int pk;
                asm("v_cvt_pk_bf16_f32 %0, %1, %2"
                    : "=v"(pk) : "v"(s4[2 * a][e]), "v"(s4[2 * a + 1][e]));
                int xk = (a * 32 + lc) ^ qsw;
                Pls[qrow + xk]        = (unsigned short)pk;
                Pls[qrow + (xk ^ 16)] = (unsigned short)(pk >> 16);
            }
        }

        __syncthreads();   // Vt/Pls complete; Kls reads done -> safe to restage

        // ---- stage next tile under PV ----
        if (t + 1 < t1) STAGE_TILE(t + 1)

        // ---- PV: O[16q x 64d] += P @ V ;  l += P @ ones ----
        {
            int qa = w * 16 + lc;
            int qrow = qa * 136, qsw = (qa & 7) << 3;
            __builtin_amdgcn_s_setprio(1);
#pragma unroll
            for (int ks2 = 0; ks2 < 4; ++ks2) {
                bf16x8 pf = *(const bf16x8*)&Pls[qrow + ((ks2 * 32 + g * 8) ^ qsw)];
#pragma unroll
                for (int nf2 = 0; nf2 < 4; ++nf2) {
                    int d = nf2 * 16 + lc;
                    bf16x8 vf = *(const bf16x8*)&Vt[d * 136 +
                                   ((ks2 * 32 + g * 8) ^ (((d >> 3) & 7) << 3))];
                    acc[nf2] = __builtin_amdgcn_mfma_f32_16x16x32_bf16(pf, vf, acc[nf2], 0, 0, 0);
                }
                lacc = __builtin_amdgcn_mfma_f32_16x16x32_bf16(pf, vones, lacc, 0, 0, 0);
            }
            __builtin_amdgcn_s_setprio(0);
        }
    }

    // ---- epilogue: lacc[e] is already the complete row sum (no reduce) ----
    if (!split) {
#pragma unroll
        for (int e = 0; e < 4; ++e) {
            int q = qbase + w * 16 + g * 4 + e;
            float inv = 1.0f / lacc[e];
            unsigned short* dst = &aout[((size_t)(b * S_ + q)) * D_ + h * DH_];
#pragma unroll
            for (int nf2 = 0; nf2 < 4; ++nf2)
                dst[nf2 * 16 + lc] = f2b(acc[nf2][e] * inv);
        }
    } else {
        int rec = ((b * 12 + h) * 5 + (qt - 11)) * 2 + half;
        float* Ob  = Opart + (size_t)rec * 8192;
        float* mlb = mlpart + rec * 256;
#pragma unroll
        for (int e = 0; e < 4; ++e) {
            int row = w * 16 + g * 4 + e;
#pragma unroll
            for (int nf2 = 0; nf2 < 4; ++nf2)
                Ob[row * 64 + nf2 * 16 + lc] = acc[nf2][e];
            if (lc == 0) { mlb[row * 2] = mrow[e]; mlb[row * 2 + 1] = lacc[e]; }
        }
    }
#undef STAGE_TILE
}

// ---------------------------------------------------------------------------
// Merge split-KV halves (log2 units): c_i = 2^(m_i - m) via v_exp_f32.
// ---------------------------------------------------------------------------
__global__ __launch_bounds__(256) void attn_merge(const float* __restrict__ Opart,
                                                  const float* __restrict__ mlpart,
                                                  unsigned short* __restrict__ aout)
{
    int rec = blockIdx.x;                 // (b*12+h)*5 + qidx
    int qidx = rec % 5;
    int bh = rec / 5;
    int h = bh % 12, b = bh / 12;
    int qt = 11 + qidx;
    int row = threadIdx.x >> 1, dbase = (threadIdx.x & 1) * 32;

    const float* O0  = Opart + ((size_t)(rec * 2 + 0)) * 8192 + row * 64 + dbase;
    const float* O1  = Opart + ((size_t)(rec * 2 + 1)) * 8192 + row * 64 + dbase;
    const float* ml0 = mlpart + (rec * 2 + 0) * 256 + row * 2;
    const float* ml1 = mlpart + (rec * 2 + 1) * 256 + row * 2;
    float m0 = ml0[0], l0 = ml0[1];
    float m1 = ml1[0], l1 = ml1[1];
    float m  = fmaxf(m0, m1);
    float c0 = fexp2(m0 - m), c1 = fexp2(m1 - m);
    float inv = 1.0f / (l0 * c0 + l1 * c1);

    int q = qt * 128 + row;
    unsigned short* dst = &aout[((size_t)(b * S_ + q)) * D_ + h * DH_ + dbase];
#pragma unroll
    for (int jj = 0; jj < 32; ++jj)
        dst[jj] = f2b((O0[jj] * c0 + O1[jj] * c1) * inv);
}

// ---------------------------------------------------------------------------
extern "C" void kernel_launch(void* const* d_in, const int* in_sizes, int n_in,
                              void* d_out, int out_size, void* d_ws, size_t ws_size,
                              hipStream_t stream)
{
    const float* x     = (const float*)d_in[0];
    const float* ctx   = (const float*)d_in[1];
    const float* ln1g  = (const float*)d_in[2];
    const float* ln1b  = (const float*)d_in[3];
    const float* Wattn = (const float*)d_in[4];
    const float* battn = (const float*)d_in[5];
    const float* Wref  = (const float*)d_in[6];
    const float* bref  = (const float*)d_in[7];
    const float* Wproj = (const float*)d_in[8];
    const float* bproj = (const float*)d_in[9];
    const float* ln2g  = (const float*)d_in[10];
    const float* ln2b  = (const float*)d_in[11];
    const float* W1    = (const float*)d_in[12];
    const float* b1    = (const float*)d_in[13];
    const float* W2    = (const float*)d_in[14];
    const float* b2    = (const float*)d_in[15];
    const float* cab   = (const float*)d_in[16];
    const int*   smp   = (const int*)d_in[17];
    float* out = (float*)d_out;

    // ---- workspace layout (float units) ----
    float* ws = (float*)d_ws;
    unsigned short* qkvb   = (unsigned short*)(ws + 0);          // 4096x2304 bf16 (steps 2-4)
    unsigned short* ff1b   = (unsigned short*)(ws + 0);          // 4096x3072 bf16 (steps 7-8)
    unsigned short* kvctxb = (unsigned short*)(ws + 4718592);    // 1024x1536 bf16
    unsigned short* attnb  = (unsigned short*)(ws + 5505024);    // 4096x768 bf16 (ends 7077888)
    unsigned short* hb     = (unsigned short*)(ws + 7077888);    // 4096x768 bf16 (ends 8650752)
    float*          x1     = ws + 8650752;                       // 4096x768 fp32 (ends 11796480)
    // attn split partials overlay hb+x1 region (dead during attention):
    float*          Opart  = ws + 7077888;                       // 3,932,160 fl (ends 11010048)
    float*          mlpart = ws + 11010048;                      // 61,440 fl  (ends 11071488)
    unsigned short* ctxb   = (unsigned short*)(ws + 11796480);   // 1024x768 bf16 (ends 12189696)
    unsigned short* wts    = (unsigned short*)(ws + 12189696);   // bf16 weights
    unsigned short* wattnT = wts;                                // 2304x768
    unsigned short* wrefT  = wts + 1769472;                      // 1536x768
    unsigned short* wprojT = wts + 2949120;                      // 768x768
    unsigned short* w1T    = wts + 3538944;                      // 3072x768
    unsigned short* w2T    = wts + 5898240;                      // 768x3072

    // 0. fused prep: 5 transposes (vectorized) + ctx convert + LN1
    wprep<<<12928, 256, 0, stream>>>(Wattn, Wref, Wproj, W1, W2, ctx, x, ln1g, ln1b,
                                     wattnT, wrefT, wprojT, w1T, w2T, ctxb, hb);
    // 1. qkv + kvctx fused GEMM (672 blocks)
    gemm_qkv_ctx<<<672, 256, 0, stream>>>(hb, wattnT, battn, qkvb,
                                          ctxb, wrefT, bref, kvctxb);
    // 2. attention (split-KV balanced, l-via-MFMA) + merge
    attn_mfma<<<504, 512, 0, stream>>>(qkvb, kvctxb, cab, smp, attnb, Opart, mlpart);
    attn_merge<<<120, 256, 0, stream>>>(Opart, mlpart, attnb);
    // 3. x1 = x + attn @ Wproj + bproj  (32x128 tile, 768 blocks, 3/CU even)
    gemm_mfma32<0, 1, 0, 0><<<dim3(6, 128), 256, 0, stream>>>(
        attnb, wprojT, bproj, x, x1, nullptr, 4096, 768, 768);
    // 4. h = LN2(x1)
    ln_kernel<<<B_ * S_, 256, 0, stream>>>(x1, ln2g, ln2b, hb);
    // 5. ff1 = silu(h @ W1 + b1)   (128x128 tile, 768 blocks)
    gemm_mfma<1, 0, 0, 1><<<dim3(24, 32), 256, 0, stream>>>(
        hb, w1T, b1, nullptr, nullptr, ff1b, 4096, 3072, 768);
    // 6. out = slice(x1 + ff1 @ W2 + b2)  (32x128 tile, 768 blocks, 3/CU even)
    gemm_mfma32<0, 1, 1, 0><<<dim3(6, 128), 256, 0, stream>>>(
        ff1b, w2T, b2, x1, out, nullptr, 4096, 768, 3072);
}

// Round 18
// 228.018 us; speedup vs baseline: 1.1443x; 1.0660x over previous
//
#include <hip/hip_runtime.h>
#include <hip/hip_bf16.h>
#include <math.h>

// Problem constants
#define B_   2
#define S_   2048
#define C_   512
#define D_   768
#define H_   12
#define DH_  64
#define DFF_ 3072
#define NS_  (C_ + S_)   // 2560
#define LOG2E_ 1.44269504f

typedef __attribute__((ext_vector_type(8))) short          bf16x8;
typedef __attribute__((ext_vector_type(4))) float          f32x4;
typedef __attribute__((ext_vector_type(8))) unsigned short us8;
typedef __attribute__((ext_vector_type(4))) unsigned short us4;

static __device__ __forceinline__ unsigned short f2b(float f) {
    unsigned int u = __float_as_uint(f);
    unsigned int r = (u + 0x7FFFu + ((u >> 16) & 1u)) >> 16;   // RNE
    return (unsigned short)r;
}
static __device__ __forceinline__ float b2f(unsigned short u) {
    return __uint_as_float(((unsigned int)u) << 16);
}
// raw v_exp_f32: D = 2^S0 (1 instruction; exp2f libm path is ~6-8)
static __device__ __forceinline__ float fexp2(float x) {
    float r;
    asm("v_exp_f32 %0, %1" : "=v"(r) : "v"(x));
    return r;
}

// async global->LDS, 16B per lane; lptr must be wave-uniform base
#define ASYNC_LDS16(gp, lp)                                                     \
    __builtin_amdgcn_global_load_lds(                                           \
        (const __attribute__((address_space(1))) void*)(gp),                    \
        (__attribute__((address_space(3))) void*)(lp), 16, 0, 0)

// XCD-chunked bijective block remap (requires nwg % 8 == 0; all call sites hold)
#define XCD_SWIZZLE_2D(MB, NB, TM, TN)                                          \
    int nwg_ = gridDim.x * gridDim.y;                                           \
    int bid_ = blockIdx.y * gridDim.x + blockIdx.x;                             \
    int q8_  = nwg_ >> 3;                                                       \
    int swz_ = (bid_ & 7) * q8_ + (bid_ >> 3);                                  \
    int MB = (swz_ / gridDim.x) * (TM);                                         \
    int NB = (swz_ % gridDim.x) * (TN);

// ---------------------------------------------------------------------------
// LayerNorm over D=768 -> bf16 out. One block (256 threads) per row.
// ---------------------------------------------------------------------------
__global__ __launch_bounds__(256) void ln_kernel(const float* __restrict__ in,
                                                 const float* __restrict__ g,
                                                 const float* __restrict__ bta,
                                                 unsigned short* __restrict__ out)
{
    int row = blockIdx.x;
    int tid = threadIdx.x;
    const float* x = in + (size_t)row * D_;
    float v0 = x[tid], v1 = x[tid + 256], v2 = x[tid + 512];
    float s  = v0 + v1 + v2;
    float s2 = v0 * v0 + v1 * v1 + v2 * v2;
#pragma unroll
    for (int off = 32; off >= 1; off >>= 1) {
        s  += __shfl_down(s,  off, 64);
        s2 += __shfl_down(s2, off, 64);
    }
    __shared__ float sh[8];
    int lane = tid & 63, wv = tid >> 6;
    if (lane == 0) { sh[wv] = s; sh[4 + wv] = s2; }
    __syncthreads();
    s  = sh[0] + sh[1] + sh[2] + sh[3];
    s2 = sh[4] + sh[5] + sh[6] + sh[7];
    float mu   = s * (1.0f / D_);
    float var  = s2 * (1.0f / D_) - mu * mu;
    float rstd = rsqrtf(var + 1e-5f);
    unsigned short* o = out + (size_t)row * D_;
    o[tid]       = f2b((v0 - mu) * rstd * g[tid]       + bta[tid]);
    o[tid + 256] = f2b((v1 - mu) * rstd * g[tid + 256] + bta[tid + 256]);
    o[tid + 512] = f2b((v2 - mu) * rstd * g[tid + 512] + bta[tid + 512]);
}

// ---------------------------------------------------------------------------
// Fused prep: 5 weight transposes (vectorized) + ctx convert + LN1.
// ---------------------------------------------------------------------------
__global__ __launch_bounds__(256) void wprep(
    const float* __restrict__ Wattn, const float* __restrict__ Wref,
    const float* __restrict__ Wproj, const float* __restrict__ W1,
    const float* __restrict__ W2,    const float* __restrict__ ctx,
    const float* __restrict__ x,     const float* __restrict__ ln1g,
    const float* __restrict__ ln1b,
    unsigned short* __restrict__ wattnT, unsigned short* __restrict__ wrefT,
    unsigned short* __restrict__ wprojT, unsigned short* __restrict__ w1T,
    unsigned short* __restrict__ w2T,    unsigned short* __restrict__ ctxb,
    unsigned short* __restrict__ hb)
{
    __shared__ float t[32][33];
    __shared__ float sh[8];
    int bid = blockIdx.x;
    int tid = threadIdx.x;

    if (bid >= 8832) {   // ---- LN1 segment ----
        int row = bid - 8832;
        const float* xr = x + (size_t)row * D_;
        float v0 = xr[tid], v1 = xr[tid + 256], v2 = xr[tid + 512];
        float s  = v0 + v1 + v2;
        float s2 = v0 * v0 + v1 * v1 + v2 * v2;
#pragma unroll
        for (int off = 32; off >= 1; off >>= 1) {
            s  += __shfl_down(s,  off, 64);
            s2 += __shfl_down(s2, off, 64);
        }
        int lane = tid & 63, wv = tid >> 6;
        if (lane == 0) { sh[wv] = s; sh[4 + wv] = s2; }
        __syncthreads();
        s  = sh[0] + sh[1] + sh[2] + sh[3];
        s2 = sh[4] + sh[5] + sh[6] + sh[7];
        float mu   = s * (1.0f / D_);
        float var  = s2 * (1.0f / D_) - mu * mu;
        float rstd = rsqrtf(var + 1e-5f);
        unsigned short* o = hb + (size_t)row * D_;
        o[tid]       = f2b((v0 - mu) * rstd * ln1g[tid]       + ln1b[tid]);
        o[tid + 256] = f2b((v1 - mu) * rstd * ln1g[tid + 256] + ln1b[tid + 256]);
        o[tid + 512] = f2b((v2 - mu) * rstd * ln1g[tid + 512] + ln1b[tid + 512]);
        return;
    }
    if (bid >= 8064) {   // ---- ctx convert ----
        int i = (bid - 8064) * 256 + tid;
        float4 v = ((const float4*)ctx)[i];
        us4 o = { f2b(v.x), f2b(v.y), f2b(v.z), f2b(v.w) };
        ((us4*)ctxb)[i] = o;
        return;
    }
    // ---- weight transpose segment (vectorized) ----
    const float* in; unsigned short* outp; int K, N, nt;
    if (bid < 1728)      {             in = Wattn; outp = wattnT; K = 768;  N = 2304; nt = 72; }
    else if (bid < 2880) { bid -= 1728; in = Wref;  outp = wrefT;  K = 768;  N = 1536; nt = 48; }
    else if (bid < 3456) { bid -= 2880; in = Wproj; outp = wprojT; K = 768;  N = 768;  nt = 24; }
    else if (bid < 5760) { bid -= 3456; in = W1;    outp = w1T;    K = 768;  N = 3072; nt = 96; }
    else                 { bid -= 5760; in = W2;    outp = w2T;    K = 3072; N = 768;  nt = 24; }
    int n0 = (bid % nt) * 32, k0 = (bid / nt) * 32;
    int r  = tid >> 3;            // 0..31
    int c4 = (tid & 7) * 4;       // 0,4,..,28
    float4 v4 = *(const float4*)&in[(size_t)(k0 + r) * N + n0 + c4];
    t[r][c4]     = v4.x;
    t[r][c4 + 1] = v4.y;
    t[r][c4 + 2] = v4.z;
    t[r][c4 + 3] = v4.w;
    __syncthreads();
    us4 ov = { f2b(t[c4][r]), f2b(t[c4 + 1][r]), f2b(t[c4 + 2][r]), f2b(t[c4 + 3][r]) };
    *(us4*)&outp[(size_t)(n0 + r) * K + k0 + c4] = ov;
}

// ---------------------------------------------------------------------------
// Shared GEMM epilogue
// ---------------------------------------------------------------------------
#define GEMM_EPI_ELEM()                                                         \
    {                                                                           \
        float v = accv[q] + bv;                                                 \
        if (ACT) v = v / (1.0f + __expf(-v));                                   \
        if (RESID) v += resid[(size_t)grow * N + gcol];                         \
        if (OUTBF) {                                                            \
            outb[(size_t)grow * N + gcol] = f2b(v);                             \
        } else if (SLICE) {                                                     \
            int bb = grow >> 11, ss = grow & 2047;                              \
            if (ss > 0)                                                         \
                outf[((size_t)(bb * 2047 + ss - 1)) * N + gcol] = v;            \
        } else {                                                                \
            outf[(size_t)grow * N + gcol] = v;                                  \
        }                                                                       \
    }

// ---------------------------------------------------------------------------
// Fused qkv + kvctx GEMM, 64x128 tiles. 1344 blocks:
// [0,1152) qkv: 18x64 grid; [1152,1344) kvctx: 12x16 grid.
// 24KB LDS -> ~5-6 blocks/CU resident (vs 2.6 at 128x128).
// ---------------------------------------------------------------------------
__global__ __launch_bounds__(256) void gemm_qkv_ctx64(
    const unsigned short* __restrict__ hb, const unsigned short* __restrict__ wattnT,
    const float* __restrict__ battn, unsigned short* __restrict__ qkvb,
    const unsigned short* __restrict__ ctxb, const unsigned short* __restrict__ wrefT,
    const float* __restrict__ bref, unsigned short* __restrict__ kvctxb)
{
    __shared__ unsigned short Als[64 * 64];   // 8KB
    __shared__ unsigned short Bls[128 * 64];  // 16KB

    int bid = blockIdx.x;
    const unsigned short *A, *BT; const float* bias; unsigned short* outb;
    int N, gx, nblk, sb;
    if (bid < 1152) { A = hb;   BT = wattnT; bias = battn; outb = qkvb;   N = 2304; gx = 18; nblk = 1152; sb = bid; }
    else            { A = ctxb; BT = wrefT;  bias = bref;  outb = kvctxb; N = 1536; gx = 12; nblk = 192;  sb = bid - 1152; }
    int swz = (sb & 7) * (nblk >> 3) + (sb >> 3);
    int mb = (swz / gx) * 64, nb = (swz % gx) * 128;
    const int K = 768;

    int tid  = threadIdx.x;
    int lane = tid & 63, w = tid >> 6;

    f32x4 acc[4][2];
#pragma unroll
    for (int m = 0; m < 4; ++m)
#pragma unroll
        for (int n = 0; n < 2; ++n)
            acc[m][n] = (f32x4){0.f, 0.f, 0.f, 0.f};

    int srow = w * 8 + (lane >> 3);           // +32 per issue
    int scol = (lane & 7) * 8;
    const unsigned short* abase = A  + (size_t)(mb + srow) * K + scol;
    const unsigned short* bbase = BT + (size_t)(nb + srow) * K + scol;

    int arow_l = lane & 15;                   // + m*16
    int brow_l = w * 32 + (lane & 15);        // + n*16
    int kfrag  = (lane >> 4) * 8;

    for (int kk = 0; kk < K; kk += 64) {
        __syncthreads();
#pragma unroll
        for (int i = 0; i < 2; ++i)
            ASYNC_LDS16(abase + (size_t)(i * 32) * K + kk,
                        (char*)Als + i * 4096 + w * 1024);
#pragma unroll
        for (int i = 0; i < 4; ++i)
            ASYNC_LDS16(bbase + (size_t)(i * 32) * K + kk,
                        (char*)Bls + i * 4096 + w * 1024);
        __syncthreads();
#pragma unroll
        for (int ks = 0; ks < 64; ks += 32) {
            bf16x8 af[4], bq[2];
#pragma unroll
            for (int m = 0; m < 4; ++m)
                af[m] = *(const bf16x8*)&Als[(arow_l + m * 16) * 64 + ks + kfrag];
#pragma unroll
            for (int n = 0; n < 2; ++n)
                bq[n] = *(const bf16x8*)&Bls[(brow_l + n * 16) * 64 + ks + kfrag];
#pragma unroll
            for (int m = 0; m < 4; ++m)
#pragma unroll
                for (int n = 0; n < 2; ++n)
                    acc[m][n] = __builtin_amdgcn_mfma_f32_16x16x32_bf16(
                        af[m], bq[n], acc[m][n], 0, 0, 0);
        }
    }

#pragma unroll
    for (int m = 0; m < 4; ++m) {
        int grow0 = mb + m * 16 + ((lane >> 4) << 2);
#pragma unroll
        for (int n = 0; n < 2; ++n) {
            int gcol = nb + w * 32 + n * 16 + (lane & 15);
            float bv = bias[gcol];
#pragma unroll
            for (int q = 0; q < 4; ++q) {
                int grow = grow0 + q;
                outb[(size_t)grow * N + gcol] = f2b(acc[m][n][q] + bv);
            }
        }
    }
}

// ---------------------------------------------------------------------------
// MFMA bf16 GEMM, 64x128 tile, 4 waves (1x4). LDS 24KB -> ~6 blocks/CU.
// ---------------------------------------------------------------------------
template <int ACT, int RESID, int SLICE, int OUTBF>
__global__ __launch_bounds__(256) void gemm_mfma64(
    const unsigned short* __restrict__ A,    // [M][K] bf16
    const unsigned short* __restrict__ BT,   // [N][K] bf16
    const float* __restrict__ bias,          // [N]
    const float* __restrict__ resid,         // [M][N] fp32 (if RESID)
    float* __restrict__ outf,                // if !OUTBF
    unsigned short* __restrict__ outb,       // if OUTBF
    int M, int N, int K)
{
    __shared__ unsigned short Als[64 * 64];   // 8KB
    __shared__ unsigned short Bls[128 * 64];  // 16KB

    int tid  = threadIdx.x;
    int lane = tid & 63, w = tid >> 6;
    XCD_SWIZZLE_2D(mb, nb, 64, 128)

    f32x4 acc[4][2];
#pragma unroll
    for (int m = 0; m < 4; ++m)
#pragma unroll
        for (int n = 0; n < 2; ++n)
            acc[m][n] = (f32x4){0.f, 0.f, 0.f, 0.f};

    int srow = w * 8 + (lane >> 3);           // +32 per issue
    int scol = (lane & 7) * 8;
    const unsigned short* abase = A  + (size_t)(mb + srow) * K + scol;
    const unsigned short* bbase = BT + (size_t)(nb + srow) * K + scol;

    int arow_l = lane & 15;                   // + m*16
    int brow_l = w * 32 + (lane & 15);        // + n*16
    int kfrag  = (lane >> 4) * 8;

    for (int kk = 0; kk < K; kk += 64) {
        __syncthreads();
#pragma unroll
        for (int i = 0; i < 2; ++i)
            ASYNC_LDS16(abase + (size_t)(i * 32) * K + kk,
                        (char*)Als + i * 4096 + w * 1024);
#pragma unroll
        for (int i = 0; i < 4; ++i)
            ASYNC_LDS16(bbase + (size_t)(i * 32) * K + kk,
                        (char*)Bls + i * 4096 + w * 1024);
        __syncthreads();
#pragma unroll
        for (int ks = 0; ks < 64; ks += 32) {
            bf16x8 af[4], bq[2];
#pragma unroll
            for (int m = 0; m < 4; ++m)
                af[m] = *(const bf16x8*)&Als[(arow_l + m * 16) * 64 + ks + kfrag];
#pragma unroll
            for (int n = 0; n < 2; ++n)
                bq[n] = *(const bf16x8*)&Bls[(brow_l + n * 16) * 64 + ks + kfrag];
#pragma unroll
            for (int m = 0; m < 4; ++m)
#pragma unroll
                for (int n = 0; n < 2; ++n)
                    acc[m][n] = __builtin_amdgcn_mfma_f32_16x16x32_bf16(
                        af[m], bq[n], acc[m][n], 0, 0, 0);
        }
    }

#pragma unroll
    for (int m = 0; m < 4; ++m) {
        int grow0 = mb + m * 16 + ((lane >> 4) << 2);
#pragma unroll
        for (int n = 0; n < 2; ++n) {
            int gcol = nb + w * 32 + n * 16 + (lane & 15);
            float bv = bias[gcol];
#pragma unroll
            for (int q = 0; q < 4; ++q) {
                int grow = grow0 + q;
                float accv[4] = {acc[m][n][0], acc[m][n][1], acc[m][n][2], acc[m][n][3]};
                GEMM_EPI_ELEM()
            }
        }
    }
}

// ---------------------------------------------------------------------------
// MFMA bf16 GEMM, 32x128 tile, 4 waves. LDS 20KB; 768-block grids -> 3/CU even.
// ---------------------------------------------------------------------------
template <int ACT, int RESID, int SLICE, int OUTBF>
__global__ __launch_bounds__(256) void gemm_mfma32(
    const unsigned short* __restrict__ A,    // [M][K] bf16
    const unsigned short* __restrict__ BT,   // [N][K] bf16
    const float* __restrict__ bias,          // [N]
    const float* __restrict__ resid,         // [M][N] fp32 (if RESID)
    float* __restrict__ outf,                // if !OUTBF
    unsigned short* __restrict__ outb,       // if OUTBF
    int M, int N, int K)
{
    __shared__ unsigned short Als[32 * 64];   // 4KB
    __shared__ unsigned short Bls[128 * 64];  // 16KB

    int tid  = threadIdx.x;
    int lane = tid & 63, w = tid >> 6;
    XCD_SWIZZLE_2D(mb, nb, 32, 128)

    f32x4 acc[2][2];
#pragma unroll
    for (int m = 0; m < 2; ++m)
#pragma unroll
        for (int n = 0; n < 2; ++n)
            acc[m][n] = (f32x4){0.f, 0.f, 0.f, 0.f};

    int srow = w * 8 + (lane >> 3);           // A: 8 rows/wave, 1 issue
    int scol = (lane & 7) * 8;
    const unsigned short* abase = A  + (size_t)(mb + srow) * K + scol;
    const unsigned short* bbase = BT + (size_t)(nb + srow) * K + scol;   // +32/issue

    int arow_l = lane & 15;                   // + m*16
    int brow_l = w * 32 + (lane & 15);        // + n*16
    int kfrag  = (lane >> 4) * 8;

    for (int kk = 0; kk < K; kk += 64) {
        __syncthreads();
        ASYNC_LDS16(abase + kk, (char*)Als + w * 1024);
#pragma unroll
        for (int i = 0; i < 4; ++i)
            ASYNC_LDS16(bbase + (size_t)(i * 32) * K + kk,
                        (char*)Bls + i * 4096 + w * 1024);
        __syncthreads();
#pragma unroll
        for (int ks = 0; ks < 64; ks += 32) {
            bf16x8 af[2], bq[2];
#pragma unroll
            for (int m = 0; m < 2; ++m)
                af[m] = *(const bf16x8*)&Als[(arow_l + m * 16) * 64 + ks + kfrag];
#pragma unroll
            for (int n = 0; n < 2; ++n)
                bq[n] = *(const bf16x8*)&Bls[(brow_l + n * 16) * 64 + ks + kfrag];
#pragma unroll
            for (int m = 0; m < 2; ++m)
#pragma unroll
                for (int n = 0; n < 2; ++n)
                    acc[m][n] = __builtin_amdgcn_mfma_f32_16x16x32_bf16(
                        af[m], bq[n], acc[m][n], 0, 0, 0);
        }
    }

#pragma unroll
    for (int m = 0; m < 2; ++m) {
        int grow0 = mb + m * 16 + ((lane >> 4) << 2);
#pragma unroll
        for (int n = 0; n < 2; ++n) {
            int gcol = nb + w * 32 + n * 16 + (lane & 15);
            float bv = bias[gcol];
#pragma unroll
            for (int q = 0; q < 4; ++q) {
                int grow = grow0 + q;
                float accv[4] = {acc[m][n][0], acc[m][n][1], acc[m][n][2], acc[m][n][3]};
                GEMM_EPI_ELEM()
            }
        }
    }
}

// ---------------------------------------------------------------------------
// Work table for attn: qt 0..10 whole; qt 11..15 split into two halves.
// ---------------------------------------------------------------------------
__device__ const int ATT_QT[21] = {10,9,8,7,6,5,15,15,14, 4,14,13,13,12, 3,12,11,11, 2,1,0};
__device__ const int ATT_T0[21] = { 0,0,0,0,0,0, 0,10, 0, 0,10, 0, 9, 0, 0, 9, 0, 8, 0,0,0};
__device__ const int ATT_T1[21] = {15,14,13,12,11,10,10,20,10, 9,19, 9,18, 9, 8,17, 8,16, 7,6,5};

// ---------------------------------------------------------------------------
// MFMA fused attention v9 (round-14 best configuration, unchanged).
// ---------------------------------------------------------------------------
__global__ __launch_bounds__(512, 2) void attn_mfma(const unsigned short* __restrict__ qkv,
                                                    const unsigned short* __restrict__ kvctx,
                                                    const float* __restrict__ cabp,
                                                    const int* __restrict__ smpp,
                                                    unsigned short* __restrict__ aout,
                                                    float* __restrict__ Opart,
                                                    float* __restrict__ mlpart)
{
    __shared__ unsigned short Kls[128 * 64];    // 16KB swizzled K tile
    __shared__ unsigned short Vt [64 * 136];    // 17KB V^T [d][k'], stride 136
    __shared__ unsigned short Pls[128 * 136];   // 34KB P [q][k'], stride 136

    int bid = blockIdx.x;
    int j = (bid < 256) ? bid : 503 - (bid - 256);   // desc-asc complementary map
    int rank = j / 24, grp = j % 24;
    int h = grp % 12, b = grp / 12;
    int qt = ATT_QT[rank], t0 = ATT_T0[rank], t1 = ATT_T1[rank];
    bool split = (t1 - t0) < (qt + 5);
    int half = (t0 > 0) ? 1 : 0;

    int tid = threadIdx.x;
    int l = tid & 63, w = tid >> 6;             // wave 0..7
    int g = l >> 4, lc = l & 15;
    float cab = *cabp;
    int   smp = *smpp;
    int qbase = qt * 128;

    // --- Q fragments (pre-scaled by log2e): q = qbase + w*16 + lc ---
    bf16x8 qf0, qf1;
    {
        const unsigned short* qp = qkv + ((size_t)(b * S_ + qbase + w * 16 + lc)) * (3 * D_)
                                       + h * DH_ + g * 8;
        qf0 = *(const bf16x8*)(qp);
        qf1 = *(const bf16x8*)(qp + 32);
#pragma unroll
        for (int i = 0; i < 8; ++i) {
            qf0[i] = (short)f2b(b2f((unsigned short)qf0[i]) * LOG2E_);
            qf1[i] = (short)f2b(b2f((unsigned short)qf1[i]) * LOG2E_);
        }
    }

    // all-ones bf16 B-fragment for the l-sum MFMA (1.0 = 0x3F80)
    bf16x8 vones;
#pragma unroll
    for (int i = 0; i < 8; ++i) vones[i] = (short)0x3F80;

    f32x4 acc[4];
#pragma unroll
    for (int n = 0; n < 4; ++n) acc[n] = (f32x4){0.f, 0.f, 0.f, 0.f};
    f32x4 lacc = (f32x4){0.f, 0.f, 0.f, 0.f};   // row-sum of P, D-layout
    float mrow[4];
#pragma unroll
    for (int e = 0; e < 4; ++e) mrow[e] = -1e30f;

    // staging lane geometry (all loop-invariant)
    int colu = 8 * ((l & 7) ^ (l >> 3));        // pre-swizzled global col (bf16)
    int kvr  = tid >> 3;                        // V k-row 0..63 (+64 second half)
    int d0   = (tid & 7) * 8;                   // V d chunk base
    int dsw  = (tid & 7) << 3;                  // Vt k-swizzle
    int vtrow[8];
#pragma unroll
    for (int jj = 0; jj < 8; ++jj) vtrow[jj] = (d0 + jj) * 136;
    int vo0 = kvr ^ dsw, vo1 = (64 + kvr) ^ dsw;
    int ksw  = (lc & 7) << 3;                   // K-read swizzle (nf-independent)
    int koff0 = (g * 8) ^ ksw, koff1 = (32 + g * 8) ^ ksw;
    us8 vr0, vr1;

#define STAGE_TILE(TT)                                                                   \
    {                                                                                    \
        int kb2 = (TT) * 128;                                                            \
        bool isctx = (kb2 < C_);                                                         \
        _Pragma("unroll")                                                                \
        for (int s2 = 0; s2 < 2; ++s2) {                                                 \
            int s = w * 2 + s2;                                                          \
            int kj = kb2 + s * 8 + (l >> 3);                                             \
            const unsigned short* src = isctx                                            \
                ? kvctx + ((size_t)(b * C_ + kj)) * (2 * D_) + h * DH_ + colu            \
                : qkv + ((size_t)(b * S_ + kj - C_)) * (3 * D_) + D_ + h * DH_ + colu;   \
            ASYNC_LDS16(src, (char*)Kls + s * 1024);                                     \
        }                                                                                \
        int kv0 = kb2 + kvr;                                                             \
        vr0 = *(const us8*)(isctx                                                        \
            ? kvctx + ((size_t)(b * C_ + kv0)) * (2 * D_) + D_ + h * DH_ + d0            \
            : qkv + ((size_t)(b * S_ + kv0 - C_)) * (3 * D_) + 2 * D_ + h * DH_ + d0);   \
        vr1 = *(const us8*)(isctx                                                        \
            ? kvctx + ((size_t)(b * C_ + kv0 + 64)) * (2 * D_) + D_ + h * DH_ + d0       \
            : qkv + ((size_t)(b * S_ + kv0 + 64 - C_)) * (3 * D_) + 2 * D_ + h * DH_ + d0); \
    }

    STAGE_TILE(t0)

    for (int t = t0; t < t1; ++t) {
        int kb = t * 128;
        __syncthreads();   // staging visible; prev PV done reading Vt/Pls

        // ---- V^T scatter: 16 stores, loop-invariant addresses ----
#pragma unroll
        for (int jj = 0; jj < 8; ++jj) {
            Vt[vtrow[jj] + vo0] = vr0[jj];
            Vt[vtrow[jj] + vo1] = vr1[jj];
        }

        // ---- QK^T: S[16q x 128k] per wave (log2 units) ----
        f32x4 s4[8];
#pragma unroll
        for (int nf = 0; nf < 8; ++nf) s4[nf] = (f32x4){0.f, 0.f, 0.f, 0.f};
        __builtin_amdgcn_s_setprio(1);
#pragma unroll
        for (int nf = 0; nf < 8; ++nf) {
            bf16x8 kf0 = *(const bf16x8*)&Kls[(nf * 16 + lc) * 64 + koff0];
            bf16x8 kf1 = *(const bf16x8*)&Kls[(nf * 16 + lc) * 64 + koff1];
            s4[nf] = __builtin_amdgcn_mfma_f32_16x16x32_bf16(qf0, kf0, s4[nf], 0, 0, 0);
            s4[nf] = __builtin_amdgcn_mfma_f32_16x16x32_bf16(qf1, kf1, s4[nf], 0, 0, 0);
        }
        __builtin_amdgcn_s_setprio(0);

        // ---- tile classification (global tile index semantics) ----
        bool edge_t = (t == qt + 4);
        bool diag_t = (kb == qbase) && (smp > 0);
        float tb = (kb < C_) ? cab * LOG2E_ : 0.0f;

        if (edge_t) {
#pragma unroll
            for (int nf = 0; nf < 8; ++nf) {
                int kj = kb + nf * 16 + lc;
#pragma unroll
                for (int e = 0; e < 4; ++e) {
                    int qi = qbase + w * 16 + g * 4 + e;
                    s4[nf][e] = (kj <= qi + C_) ? s4[nf][e] : -100000.0f;
                }
            }
        }
        if (diag_t) {
#pragma unroll
            for (int nf = 0; nf < 8; ++nf) {
                int kj = kb + nf * 16 + lc;
#pragma unroll
                for (int e = 0; e < 4; ++e) {
                    int qi = qbase + w * 16 + g * 4 + e;
                    if (kj == qi) s4[nf][e] = -100000.0f;
                }
            }
        }

        // ---- online softmax (log2 units, raw v_exp_f32, l via MFMA) ----
        float tmax[4], mbase[4];
#pragma unroll
        for (int e = 0; e < 4; ++e) {
            float u0 = fmaxf(fmaxf(s4[0][e], s4[1][e]), fmaxf(s4[2][e], s4[3][e]));
            float u1 = fmaxf(fmaxf(s4[4][e], s4[5][e]), fmaxf(s4[6][e], s4[7][e]));
            tmax[e] = fmaxf(u0, u1);
        }
#pragma unroll
        for (int e = 0; e < 4; ++e) {
            tmax[e] = fmaxf(tmax[e], __shfl_xor(tmax[e], 1));
            tmax[e] = fmaxf(tmax[e], __shfl_xor(tmax[e], 2));
            tmax[e] = fmaxf(tmax[e], __shfl_xor(tmax[e], 4));
            tmax[e] = fmaxf(tmax[e], __shfl_xor(tmax[e], 8));
        }
#pragma unroll
        for (int e = 0; e < 4; ++e) {
            float mn = fmaxf(mrow[e], tmax[e] + tb);
            if (mn > mrow[e]) {                      // defer-rescale (O and l together)
                float sc = fexp2(mrow[e] - mn);
#pragma unroll
                for (int nf2 = 0; nf2 < 4; ++nf2) acc[nf2][e] *= sc;
                lacc[e] *= sc;
                mrow[e] = mn;
            }
            mbase[e] = mrow[e] - tb;
        }
#pragma unroll
        for (int nf = 0; nf < 8; ++nf)
#pragma unroll
            for (int e = 0; e < 4; ++e)
                s4[nf][e] = fexp2(s4[nf][e] - mbase[e]);

        // ---- P -> bf16 via cvt_pk -> swizzled LDS (offset XOR before +base) ----
#pragma unroll
        for (int e = 0; e < 4; ++e) {
            int q = w * 16 + g * 4 + e;
            int qrow = q * 136, qsw = (q & 7) << 3;
#pragma unroll
            for (int a = 0; a < 4; ++a) {
                unsigned int pk;
                asm("v_cvt_pk_bf16_f32 %0, %1, %2"
                    : "=v"(pk) : "v"(s4[2 * a][e]), "v"(s4[2 * a + 1][e]));
                int xk = (a * 32 + lc) ^ qsw;
                Pls[qrow + xk]        = (unsigned short)pk;
                Pls[qrow + (xk ^ 16)] = (unsigned short)(pk >> 16);
            }
        }

        __syncthreads();   // Vt/Pls complete; Kls reads done -> safe to restage

        // ---- stage next tile under PV ----
        if (t + 1 < t1) STAGE_TILE(t + 1)

        // ---- PV: O[16q x 64d] += P @ V ;  l += P @ ones ----
        {
            int qa = w * 16 + lc;
            int qrow = qa * 136, qsw = (qa & 7) << 3;
            __builtin_amdgcn_s_setprio(1);
#pragma unroll
            for (int ks2 = 0; ks2 < 4; ++ks2) {
                bf16x8 pf = *(const bf16x8*)&Pls[qrow + ((ks2 * 32 + g * 8) ^ qsw)];
#pragma unroll
                for (int nf2 = 0; nf2 < 4; ++nf2) {
                    int d = nf2 * 16 + lc;
                    bf16x8 vf = *(const bf16x8*)&Vt[d * 136 +
                                   ((ks2 * 32 + g * 8) ^ (((d >> 3) & 7) << 3))];
                    acc[nf2] = __builtin_amdgcn_mfma_f32_16x16x32_bf16(pf, vf, acc[nf2], 0, 0, 0);
                }
                lacc = __builtin_amdgcn_mfma_f32_16x16x32_bf16(pf, vones, lacc, 0, 0, 0);
            }
            __builtin_amdgcn_s_setprio(0);
        }
    }

    // ---- epilogue: lacc[e] is already the complete row sum (no reduce) ----
    if (!split) {
#pragma unroll
        for (int e = 0; e < 4; ++e) {
            int q = qbase + w * 16 + g * 4 + e;
            float inv = 1.0f / lacc[e];
            unsigned short* dst = &aout[((size_t)(b * S_ + q)) * D_ + h * DH_];
#pragma unroll
            for (int nf2 = 0; nf2 < 4; ++nf2)
                dst[nf2 * 16 + lc] = f2b(acc[nf2][e] * inv);
        }
    } else {
        int rec = ((b * 12 + h) * 5 + (qt - 11)) * 2 + half;
        float* Ob  = Opart + (size_t)rec * 8192;
        float* mlb = mlpart + rec * 256;
#pragma unroll
        for (int e = 0; e < 4; ++e) {
            int row = w * 16 + g * 4 + e;
#pragma unroll
            for (int nf2 = 0; nf2 < 4; ++nf2)
                Ob[row * 64 + nf2 * 16 + lc] = acc[nf2][e];
            if (lc == 0) { mlb[row * 2] = mrow[e]; mlb[row * 2 + 1] = lacc[e]; }
        }
    }
#undef STAGE_TILE
}

// ---------------------------------------------------------------------------
// Merge split-KV halves (log2 units): c_i = 2^(m_i - m) via v_exp_f32.
// ---------------------------------------------------------------------------
__global__ __launch_bounds__(256) void attn_merge(const float* __restrict__ Opart,
                                                  const float* __restrict__ mlpart,
                                                  unsigned short* __restrict__ aout)
{
    int rec = blockIdx.x;                 // (b*12+h)*5 + qidx
    int qidx = rec % 5;
    int bh = rec / 5;
    int h = bh % 12, b = bh / 12;
    int qt = 11 + qidx;
    int row = threadIdx.x >> 1, dbase = (threadIdx.x & 1) * 32;

    const float* O0  = Opart + ((size_t)(rec * 2 + 0)) * 8192 + row * 64 + dbase;
    const float* O1  = Opart + ((size_t)(rec * 2 + 1)) * 8192 + row * 64 + dbase;
    const float* ml0 = mlpart + (rec * 2 + 0) * 256 + row * 2;
    const float* ml1 = mlpart + (rec * 2 + 1) * 256 + row * 2;
    float m0 = ml0[0], l0 = ml0[1];
    float m1 = ml1[0], l1 = ml1[1];
    float m  = fmaxf(m0, m1);
    float c0 = fexp2(m0 - m), c1 = fexp2(m1 - m);
    float inv = 1.0f / (l0 * c0 + l1 * c1);

    int q = qt * 128 + row;
    unsigned short* dst = &aout[((size_t)(b * S_ + q)) * D_ + h * DH_ + dbase];
#pragma unroll
    for (int jj = 0; jj < 32; ++jj)
        dst[jj] = f2b((O0[jj] * c0 + O1[jj] * c1) * inv);
}

// ---------------------------------------------------------------------------
extern "C" void kernel_launch(void* const* d_in, const int* in_sizes, int n_in,
                              void* d_out, int out_size, void* d_ws, size_t ws_size,
                              hipStream_t stream)
{
    const float* x     = (const float*)d_in[0];
    const float* ctx   = (const float*)d_in[1];
    const float* ln1g  = (const float*)d_in[2];
    const float* ln1b  = (const float*)d_in[3];
    const float* Wattn = (const float*)d_in[4];
    const float* battn = (const float*)d_in[5];
    const float* Wref  = (const float*)d_in[6];
    const float* bref  = (const float*)d_in[7];
    const float* Wproj = (const float*)d_in[8];
    const float* bproj = (const float*)d_in[9];
    const float* ln2g  = (const float*)d_in[10];
    const float* ln2b  = (const float*)d_in[11];
    const float* W1    = (const float*)d_in[12];
    const float* b1    = (const float*)d_in[13];
    const float* W2    = (const float*)d_in[14];
    const float* b2    = (const float*)d_in[15];
    const float* cab   = (const float*)d_in[16];
    const int*   smp   = (const int*)d_in[17];
    float* out = (float*)d_out;

    // ---- workspace layout (float units) ----
    float* ws = (float*)d_ws;
    unsigned short* qkvb   = (unsigned short*)(ws + 0);          // 4096x2304 bf16 (steps 2-4)
    unsigned short* ff1b   = (unsigned short*)(ws + 0);          // 4096x3072 bf16 (steps 7-8)
    unsigned short* kvctxb = (unsigned short*)(ws + 4718592);    // 1024x1536 bf16
    unsigned short* attnb  = (unsigned short*)(ws + 5505024);    // 4096x768 bf16 (ends 7077888)
    unsigned short* hb     = (unsigned short*)(ws + 7077888);    // 4096x768 bf16 (ends 8650752)
    float*          x1     = ws + 8650752;                       // 4096x768 fp32 (ends 11796480)
    // attn split partials overlay hb+x1 region (dead during attention):
    float*          Opart  = ws + 7077888;                       // 3,932,160 fl (ends 11010048)
    float*          mlpart = ws + 11010048;                      // 61,440 fl  (ends 11071488)
    unsigned short* ctxb   = (unsigned short*)(ws + 11796480);   // 1024x768 bf16 (ends 12189696)
    unsigned short* wts    = (unsigned short*)(ws + 12189696);   // bf16 weights
    unsigned short* wattnT = wts;                                // 2304x768
    unsigned short* wrefT  = wts + 1769472;                      // 1536x768
    unsigned short* wprojT = wts + 2949120;                      // 768x768
    unsigned short* w1T    = wts + 3538944;                      // 3072x768
    unsigned short* w2T    = wts + 5898240;                      // 768x3072

    // 0. fused prep: 5 transposes (vectorized) + ctx convert + LN1
    wprep<<<12928, 256, 0, stream>>>(Wattn, Wref, Wproj, W1, W2, ctx, x, ln1g, ln1b,
                                     wattnT, wrefT, wprojT, w1T, w2T, ctxb, hb);
    // 1. qkv + kvctx fused GEMM (64x128 tiles, 1344 blocks = 5.25/CU)
    gemm_qkv_ctx64<<<1344, 256, 0, stream>>>(hb, wattnT, battn, qkvb,
                                             ctxb, wrefT, bref, kvctxb);
    // 2. attention (split-KV balanced, l-via-MFMA) + merge
    attn_mfma<<<504, 512, 0, stream>>>(qkvb, kvctxb, cab, smp, attnb, Opart, mlpart);
    attn_merge<<<120, 256, 0, stream>>>(Opart, mlpart, attnb);
    // 3. x1 = x + attn @ Wproj + bproj  (32x128 tile, 768 blocks, 3/CU even)
    gemm_mfma32<0, 1, 0, 0><<<dim3(6, 128), 256, 0, stream>>>(
        attnb, wprojT, bproj, x, x1, nullptr, 4096, 768, 768);
    // 4. h = LN2(x1)
    ln_kernel<<<B_ * S_, 256, 0, stream>>>(x1, ln2g, ln2b, hb);
    // 5. ff1 = silu(h @ W1 + b1)   (64x128 tile, 1536 blocks = 6/CU)
    gemm_mfma64<1, 0, 0, 1><<<dim3(24, 64), 256, 0, stream>>>(
        hb, w1T, b1, nullptr, nullptr, ff1b, 4096, 3072, 768);
    // 6. out = slice(x1 + ff1 @ W2 + b2)  (32x128 tile, 768 blocks, 3/CU even)
    gemm_mfma32<0, 1, 1, 0><<<dim3(6, 128), 256, 0, stream>>>(
        ff1b, w2T, b2, x1, out, nullptr, 4096, 768, 3072);
}